// Round 1
// baseline (810.190 us; speedup 1.0000x reference)
//
#include <hip/hip_runtime.h>
#include <math.h>

#define D_MODEL 768
#define SEQ 2048
#define D_STATE 64
#define D_CONV 4
#define D_INNER 1536
#define HEADDIM 64
#define NHEADS 24
#define CONV_DIM 1664      // D_INNER + 2*D_STATE
#define D_IN_PROJ 3224     // 2*D_INNER + 2*D_STATE + NHEADS
#define HIDDEN 1536
#define EPS 1e-5f
#define NCHUNK 32
#define CHUNK 64

// ---------------- block-wide sum over 256 threads (4 waves of 64) -----------
__device__ __forceinline__ float block_sum256(float v, float* sdata) {
#pragma unroll
  for (int o = 32; o > 0; o >>= 1) v += __shfl_down(v, o);
  int lane = threadIdx.x & 63, wid = threadIdx.x >> 6;
  __syncthreads();
  if (lane == 0) sdata[wid] = v;
  __syncthreads();
  if (threadIdx.x == 0) sdata[0] = sdata[0] + sdata[1] + sdata[2] + sdata[3];
  __syncthreads();
  return sdata[0];
}

__device__ __forceinline__ float silu_f(float x) {
  return x / (1.f + expf(-x));
}

// ---------------- LayerNorm over D_MODEL=768, one block per row -------------
__global__ __launch_bounds__(256) void ln_kernel(const float* __restrict__ x,
                                                 const float* __restrict__ w,
                                                 const float* __restrict__ b,
                                                 float* __restrict__ out) {
  __shared__ float red[8];
  int row = blockIdx.x;
  const float* xr = x + (size_t)row * D_MODEL;
  float v[3];
#pragma unroll
  for (int k = 0; k < 3; k++) v[k] = xr[threadIdx.x + k * 256];
  float s = v[0] + v[1] + v[2];
  s = block_sum256(s, red);
  float mean = s * (1.f / 768.f);
  float q = 0.f;
#pragma unroll
  for (int k = 0; k < 3; k++) { float d = v[k] - mean; q += d * d; }
  q = block_sum256(q, red);
  float rstd = rsqrtf(q * (1.f / 768.f) + EPS);
  float* orow = out + (size_t)row * D_MODEL;
#pragma unroll
  for (int k = 0; k < 3; k++) {
    int i = threadIdx.x + k * 256;
    orow[i] = (v[k] - mean) * rstd * w[i] + b[i];
  }
}

// ---------------- fp32 tiled GEMM: C = A(MxK,row) * B(NxK,row)^T (+res) -----
#define BM 64
#define BN 64
#define BK 16
__global__ __launch_bounds__(256) void sgemm_nt(const float* __restrict__ A,
                                                const float* __restrict__ B,
                                                float* __restrict__ C,
                                                int M, int N, int K,
                                                const float* __restrict__ res) {
  __shared__ float As[BK][BM];
  __shared__ float Bs[BK][BN];
  int tid = threadIdx.x;
  int tx = tid & 15, ty = tid >> 4;
  int m0 = blockIdx.y * BM, n0 = blockIdx.x * BN;
  float acc[4][4] = {};
  int lrow = tid >> 2;        // 0..63
  int lk4  = (tid & 3) * 4;   // 0,4,8,12

  for (int kt = 0; kt < K; kt += BK) {
    float4 av = *(const float4*)(A + (size_t)(m0 + lrow) * K + kt + lk4);
    int brow = n0 + lrow;
    float4 bv = make_float4(0.f, 0.f, 0.f, 0.f);
    if (brow < N) bv = *(const float4*)(B + (size_t)brow * K + kt + lk4);
    __syncthreads();
    As[lk4 + 0][lrow] = av.x; As[lk4 + 1][lrow] = av.y;
    As[lk4 + 2][lrow] = av.z; As[lk4 + 3][lrow] = av.w;
    Bs[lk4 + 0][lrow] = bv.x; Bs[lk4 + 1][lrow] = bv.y;
    Bs[lk4 + 2][lrow] = bv.z; Bs[lk4 + 3][lrow] = bv.w;
    __syncthreads();
#pragma unroll
    for (int kk = 0; kk < BK; kk++) {
      float a[4], bb[4];
      *(float4*)a  = *(const float4*)&As[kk][ty * 4];
      *(float4*)bb = *(const float4*)&Bs[kk][tx * 4];
#pragma unroll
      for (int i = 0; i < 4; i++)
#pragma unroll
        for (int j = 0; j < 4; j++)
          acc[i][j] += a[i] * bb[j];
    }
  }
#pragma unroll
  for (int i = 0; i < 4; i++) {
    int m = m0 + ty * 4 + i;
#pragma unroll
    for (int j = 0; j < 4; j++) {
      int n = n0 + tx * 4 + j;
      if (n < N) {
        float v = acc[i][j];
        if (res) v += res[(size_t)m * N + n];
        C[(size_t)m * N + n] = v;
      }
    }
  }
}

// ---------------- causal depthwise conv4 + bias + SiLU -----------------------
__global__ void conv_silu_kernel(const float* __restrict__ zx,
                                 const float* __restrict__ cw,
                                 const float* __restrict__ cb,
                                 float* __restrict__ xbc) {
  int idx = blockIdx.x * 256 + threadIdx.x;
  if (idx >= SEQ * CONV_DIM) return;
  int t = idx / CONV_DIM, c = idx % CONV_DIM;
  float acc = cb[c];
#pragma unroll
  for (int k = 0; k < D_CONV; k++) {
    int tt = t + k - (D_CONV - 1);
    if (tt >= 0) acc += zx[(size_t)tt * D_IN_PROJ + D_INNER + c] * cw[c * D_CONV + k];
  }
  xbc[idx] = silu_f(acc);
}

// ---------------- dt = softplus(dt_raw + bias); dA = exp(-exp(A_log)*dt) ----
__global__ void dt_kernel(const float* __restrict__ zx,
                          const float* __restrict__ dtb,
                          const float* __restrict__ Alog,
                          float* __restrict__ dts, float* __restrict__ dab) {
  int idx = blockIdx.x * 256 + threadIdx.x;
  if (idx >= SEQ * NHEADS) return;
  int t = idx / NHEADS, hh = idx % NHEADS;
  float xv = zx[(size_t)t * D_IN_PROJ + 2 * D_INNER + 2 * D_STATE + hh] + dtb[hh];
  float sp = (xv > 20.f) ? xv : log1pf(expf(xv));
  dts[idx] = sp;
  dab[idx] = expf(-expf(Alog[hh]) * sp);
}

// ---------------- scan pass 1: per-(chunk,head) local scan from zero --------
__global__ __launch_bounds__(64) void scan1_kernel(const float* __restrict__ xbc,
                                                   const float* __restrict__ dts,
                                                   const float* __restrict__ dab,
                                                   float* __restrict__ ylocal,
                                                   float* __restrict__ cumdA,
                                                   float* __restrict__ Sbuf) {
  int c = blockIdx.x / NHEADS;
  int hh = blockIdx.x % NHEADS;
  int p = threadIdx.x;
  float hst[64];
#pragma unroll
  for (int i = 0; i < 64; i++) hst[i] = 0.f;
  float cd = 1.f;
  int t0 = c * CHUNK;
  for (int tt = 0; tt < CHUNK; ++tt) {
    int t = t0 + tt;
    float dAv = dab[t * NHEADS + hh];
    float dtp = dts[t * NHEADS + hh] * xbc[(size_t)t * CONV_DIM + hh * 64 + p];
    cd *= dAv;
    if (p == 0) cumdA[t * NHEADS + hh] = cd;
    float y = 0.f;
    const float4* Bv4 = (const float4*)(xbc + (size_t)t * CONV_DIM + D_INNER);
    const float4* Cv4 = (const float4*)(xbc + (size_t)t * CONV_DIM + D_INNER + D_STATE);
#pragma unroll
    for (int sb = 0; sb < 16; ++sb) {
      float4 Bv = Bv4[sb];
      float4 Cv = Cv4[sb];
      hst[4 * sb + 0] = hst[4 * sb + 0] * dAv + dtp * Bv.x;  y += hst[4 * sb + 0] * Cv.x;
      hst[4 * sb + 1] = hst[4 * sb + 1] * dAv + dtp * Bv.y;  y += hst[4 * sb + 1] * Cv.y;
      hst[4 * sb + 2] = hst[4 * sb + 2] * dAv + dtp * Bv.z;  y += hst[4 * sb + 2] * Cv.z;
      hst[4 * sb + 3] = hst[4 * sb + 3] * dAv + dtp * Bv.w;  y += hst[4 * sb + 3] * Cv.w;
    }
    ylocal[(size_t)t * D_INNER + hh * 64 + p] = y;
  }
  float* Sp = Sbuf + (((size_t)c * NHEADS + hh) * 64 + p) * 64;
#pragma unroll
  for (int sb = 0; sb < 16; ++sb)
    *(float4*)(Sp + 4 * sb) =
        make_float4(hst[4 * sb], hst[4 * sb + 1], hst[4 * sb + 2], hst[4 * sb + 3]);
}

// ---------------- scan pass 2: sequential chunk combine (in place S->hstart) -
__global__ __launch_bounds__(64) void scan2_kernel(float* __restrict__ Sbuf,
                                                   const float* __restrict__ cumdA) {
  int hh = blockIdx.x;
  int p = threadIdx.x;
  float run[64];
#pragma unroll
  for (int i = 0; i < 64; i++) run[i] = 0.f;
  for (int c = 0; c < NCHUNK; c++) {
    float P = cumdA[(c * CHUNK + CHUNK - 1) * NHEADS + hh];
    float* Sp = Sbuf + (((size_t)c * NHEADS + hh) * 64 + p) * 64;
#pragma unroll
    for (int sb = 0; sb < 16; sb++) {
      float4 S = *(float4*)(Sp + 4 * sb);
      *(float4*)(Sp + 4 * sb) =
          make_float4(run[4 * sb], run[4 * sb + 1], run[4 * sb + 2], run[4 * sb + 3]);
      run[4 * sb + 0] = P * run[4 * sb + 0] + S.x;
      run[4 * sb + 1] = P * run[4 * sb + 1] + S.y;
      run[4 * sb + 2] = P * run[4 * sb + 2] + S.z;
      run[4 * sb + 3] = P * run[4 * sb + 3] + S.w;
    }
  }
}

// ------ scan pass 3 + D_skip + z-gate + RMSNorm, one block per timestep -----
__global__ __launch_bounds__(256) void ssm_finish_kernel(
    const float* __restrict__ xbc, const float* __restrict__ zx,
    const float* __restrict__ cumdA, const float* __restrict__ Sbuf,
    const float* __restrict__ Dsk, const float* __restrict__ nw,
    float* __restrict__ ybuf) {
  __shared__ float Cs[64];
  __shared__ float red[8];
  int t = blockIdx.x;
  int c = t / CHUNK;
  if (threadIdx.x < 64)
    Cs[threadIdx.x] = xbc[(size_t)t * CONV_DIM + D_INNER + D_STATE + threadIdx.x];
  __syncthreads();
  float yg[6];
  float ss = 0.f;
#pragma unroll
  for (int k = 0; k < 6; k++) {
    int i = threadIdx.x + k * 256;
    int hh = i >> 6, p = i & 63;
    const float* hs = Sbuf + (((size_t)c * NHEADS + hh) * 64 + p) * 64;
    float dot = 0.f;
#pragma unroll
    for (int sb = 0; sb < 16; sb++) {
      float4 h4 = *(const float4*)(hs + 4 * sb);
      dot += h4.x * Cs[4 * sb] + h4.y * Cs[4 * sb + 1] +
             h4.z * Cs[4 * sb + 2] + h4.w * Cs[4 * sb + 3];
    }
    float y = ybuf[(size_t)t * D_INNER + i] + cumdA[t * NHEADS + hh] * dot +
              Dsk[hh] * xbc[(size_t)t * CONV_DIM + i];
    float z = zx[(size_t)t * D_IN_PROJ + i];
    float g = y * silu_f(z);
    yg[k] = g;
    ss += g * g;
  }
  ss = block_sum256(ss, red);
  float rs = rsqrtf(ss * (1.f / (float)D_INNER) + EPS);
#pragma unroll
  for (int k = 0; k < 6; k++) {
    int i = threadIdx.x + k * 256;
    ybuf[(size_t)t * D_INNER + i] = yg[k] * rs * nw[i];
  }
}

// ---------------- GLU: g = f[:, :H] * silu(f[:, H:2H]) ----------------------
__global__ void glu_kernel(const float* __restrict__ f, float* __restrict__ g) {
  int idx = blockIdx.x * 256 + threadIdx.x;
  if (idx >= SEQ * HIDDEN) return;
  int t = idx / HIDDEN, i = idx % HIDDEN;
  float a = f[(size_t)t * 2 * HIDDEN + i];
  float b = f[(size_t)t * 2 * HIDDEN + HIDDEN + i];
  g[idx] = a * silu_f(b);
}

// ----------------------------------------------------------------------------
extern "C" void kernel_launch(void* const* d_in, const int* in_sizes, int n_in,
                              void* d_out, int out_size, void* d_ws, size_t ws_size,
                              hipStream_t stream) {
  const float* x     = (const float*)d_in[0];
  const float* ln1w  = (const float*)d_in[1];
  const float* ln1b  = (const float*)d_in[2];
  const float* ln2w  = (const float*)d_in[3];
  const float* ln2b  = (const float*)d_in[4];
  const float* Win   = (const float*)d_in[5];
  const float* convw = (const float*)d_in[6];
  const float* convb = (const float*)d_in[7];
  const float* dtb   = (const float*)d_in[8];
  const float* Alog  = (const float*)d_in[9];
  const float* Dsk   = (const float*)d_in[10];
  const float* nrmw  = (const float*)d_in[11];
  const float* Wout  = (const float*)d_in[12];
  const float* Wfc1  = (const float*)d_in[13];
  const float* Wfc2  = (const float*)d_in[14];
  float* out = (float*)d_out;
  float* ws  = (float*)d_ws;

  float* h   = ws;                 // 2048*768   = 1,572,864
  float* zx  = h + 1572864;        // 2048*3224  = 6,602,752
  float* xbc = zx + 6602752;       // 2048*1664  = 3,407,872
  float* dts = xbc + 3407872;      // 2048*24    = 49,152
  float* dab = dts + 49152;        // 49,152
  float* cda = dab + 49152;        // 49,152
  float* yb  = cda + 49152;        // 2048*1536  = 3,145,728
  float* Sb  = yb + 3145728;       // 32*24*64*64= 3,145,728
  float* x1  = Sb + 3145728;       // 1,572,864   (total ~78.4 MB)
  float* f   = zx;                 // reuse zx region (zx dead after ssm_finish)
  float* g   = xbc;                // reuse xbc region

  // 1) LN1
  ln_kernel<<<SEQ, 256, 0, stream>>>(x, ln1w, ln1b, h);
  // 2) in_proj: zx = h @ Win^T   (2048 x 3224)
  sgemm_nt<<<dim3((D_IN_PROJ + BN - 1) / BN, SEQ / BM), 256, 0, stream>>>(
      h, Win, zx, SEQ, D_IN_PROJ, D_MODEL, nullptr);
  // 3) conv + silu
  conv_silu_kernel<<<(SEQ * CONV_DIM + 255) / 256, 256, 0, stream>>>(zx, convw, convb, xbc);
  // 4) dt / dA
  dt_kernel<<<(SEQ * NHEADS + 255) / 256, 256, 0, stream>>>(zx, dtb, Alog, dts, dab);
  // 5) chunked scan
  scan1_kernel<<<NCHUNK * NHEADS, 64, 0, stream>>>(xbc, dts, dab, yb, cda, Sb);
  scan2_kernel<<<NHEADS, 64, 0, stream>>>(Sb, cda);
  ssm_finish_kernel<<<SEQ, 256, 0, stream>>>(xbc, zx, cda, Sb, Dsk, nrmw, yb);
  // 6) out_proj + residual: x1 = x + yb @ Wout^T
  sgemm_nt<<<dim3(D_MODEL / BN, SEQ / BM), 256, 0, stream>>>(
      yb, Wout, x1, SEQ, D_MODEL, D_INNER, x);
  // 7) LN2
  ln_kernel<<<SEQ, 256, 0, stream>>>(x1, ln2w, ln2b, h);
  // 8) fc1: f = h @ Wfc1^T (2048 x 3072)
  sgemm_nt<<<dim3((2 * HIDDEN) / BN, SEQ / BM), 256, 0, stream>>>(
      h, Wfc1, f, SEQ, 2 * HIDDEN, D_MODEL, nullptr);
  // 9) GLU
  glu_kernel<<<(SEQ * HIDDEN + 255) / 256, 256, 0, stream>>>(f, g);
  // 10) fc2 + residual: out = x1 + g @ Wfc2^T
  sgemm_nt<<<dim3(D_MODEL / BN, SEQ / BM), 256, 0, stream>>>(
      g, Wfc2, out, SEQ, D_MODEL, HIDDEN, x1);
}

// Round 2
// 343.272 us; speedup vs baseline: 2.3602x; 2.3602x over previous
//
#include <hip/hip_runtime.h>
#include <math.h>

#define D_MODEL 768
#define SEQ 2048
#define D_STATE 64
#define D_CONV 4
#define D_INNER 1536
#define HEADDIM 64
#define NHEADS 24
#define CONV_DIM 1664      // D_INNER + 2*D_STATE
#define D_IN_PROJ 3224     // 2*D_INNER + 2*D_STATE + NHEADS
#define HIDDEN 1536
#define EPS 1e-5f
#define NCHUNK 32
#define CHUNK 64

typedef short s16x8 __attribute__((ext_vector_type(8)));
typedef float f32x4 __attribute__((ext_vector_type(4)));

// ---------------- helpers ---------------------------------------------------
__device__ __forceinline__ float silu_f(float x) { return x / (1.f + expf(-x)); }

__device__ __forceinline__ short f2bf(float x) {  // RNE fp32 -> bf16 bits
  unsigned u = __builtin_bit_cast(unsigned, x);
  unsigned r = (u + 0x7fffu + ((u >> 16) & 1u)) >> 16;
  return (short)r;
}

__device__ __forceinline__ float block_sum256(float v, float* sdata) {
#pragma unroll
  for (int o = 32; o > 0; o >>= 1) v += __shfl_down(v, o);
  int lane = threadIdx.x & 63, wid = threadIdx.x >> 6;
  __syncthreads();
  if (lane == 0) sdata[wid] = v;
  __syncthreads();
  if (threadIdx.x == 0) sdata[0] = sdata[0] + sdata[1] + sdata[2] + sdata[3];
  __syncthreads();
  return sdata[0];
}

// async 16B global->LDS (linear dest: wave-uniform base + lane*16)
__device__ __forceinline__ void gll16(const short* gsrc, const short* ldst) {
  __builtin_amdgcn_global_load_lds(
      (const __attribute__((address_space(1))) unsigned int*)(unsigned long long)gsrc,
      (__attribute__((address_space(3))) unsigned int*)(unsigned int)(unsigned long long)ldst,
      16, 0, 0);
}

// ---------------- LayerNorm over 768, writes bf16 ---------------------------
__global__ __launch_bounds__(256) void ln_kernel(const float* __restrict__ x,
                                                 const float* __restrict__ w,
                                                 const float* __restrict__ b,
                                                 short* __restrict__ out) {
  __shared__ float red[8];
  int row = blockIdx.x;
  const float* xr = x + (size_t)row * D_MODEL;
  float v[3];
#pragma unroll
  for (int k = 0; k < 3; k++) v[k] = xr[threadIdx.x + k * 256];
  float s = v[0] + v[1] + v[2];
  s = block_sum256(s, red);
  float mean = s * (1.f / 768.f);
  float q = 0.f;
#pragma unroll
  for (int k = 0; k < 3; k++) { float d = v[k] - mean; q += d * d; }
  q = block_sum256(q, red);
  float rstd = rsqrtf(q * (1.f / 768.f) + EPS);
  short* orow = out + (size_t)row * D_MODEL;
#pragma unroll
  for (int k = 0; k < 3; k++) {
    int i = threadIdx.x + k * 256;
    orow[i] = f2bf((v[k] - mean) * rstd * w[i] + b[i]);
  }
}

// ---------------- weight cast fp32 -> bf16 with row padding -----------------
__global__ void castpad_kernel(const float* __restrict__ src, short* __restrict__ dst,
                               int total, int realtotal) {
  int idx = blockIdx.x * 256 + threadIdx.x;
  if (idx >= total) return;
  dst[idx] = (idx < realtotal) ? f2bf(src[idx]) : (short)0;
}

// ---------------- bf16 MFMA GEMM: C = A(MxK) * W(NpadxK)^T (+res) -----------
// MREP=4 -> 128x128 tile; MREP=2 -> 64x128 tile. 256 threads = 4 waves (2x2).
template <int MREP>
__global__ __launch_bounds__(256) void mfma_gemm_bt(const short* __restrict__ A,
                                                    const short* __restrict__ Bw,
                                                    float* __restrict__ C,
                                                    const float* __restrict__ res,
                                                    int M, int Nreal, int K) {
  constexpr int BMr = MREP * 32;
  __shared__ short As[BMr * 32];
  __shared__ short Bs[128 * 32];
  int tid = threadIdx.x, w = tid >> 6, l = tid & 63;
  int m0 = blockIdx.y * BMr, n0 = blockIdx.x * 128;
  int wr = (w >> 1) * (MREP * 16), wc = (w & 1) * 64;
  f32x4 acc[MREP][4] = {};

  for (int kt = 0; kt < K; kt += 32) {
    __syncthreads();
    // stage A tile (BMr x 32 bf16), LDS linear, global source slot-swizzled
#pragma unroll
    for (int q = 0; q < BMr / 64; q++) {
      int chunk = w * (BMr / 64) + q;      // 16-row chunk
      int row = chunk * 16 + (l >> 2);
      int gs = (l & 3) ^ (row & 3);
      gll16(A + (size_t)(m0 + row) * K + kt + gs * 8, As + chunk * 512);
    }
    // stage B tile (128 x 32 bf16)
#pragma unroll
    for (int q = 0; q < 2; q++) {
      int chunk = w * 2 + q;
      int row = chunk * 16 + (l >> 2);
      int gs = (l & 3) ^ (row & 3);
      gll16(Bw + (size_t)(n0 + row) * K + kt + gs * 8, Bs + chunk * 512);
    }
    __syncthreads();
    s16x8 af[MREP], bfr[4];
#pragma unroll
    for (int mi = 0; mi < MREP; mi++) {
      int row = wr + mi * 16 + (l & 15);
      int sl = (l >> 4) ^ (row & 3);
      af[mi] = *(const s16x8*)&As[row * 32 + sl * 8];
    }
#pragma unroll
    for (int nj = 0; nj < 4; nj++) {
      int row = wc + nj * 16 + (l & 15);
      int sl = (l >> 4) ^ (row & 3);
      bfr[nj] = *(const s16x8*)&Bs[row * 32 + sl * 8];
    }
#pragma unroll
    for (int mi = 0; mi < MREP; mi++)
#pragma unroll
      for (int nj = 0; nj < 4; nj++)
        acc[mi][nj] = __builtin_amdgcn_mfma_f32_16x16x32_bf16(af[mi], bfr[nj],
                                                              acc[mi][nj], 0, 0, 0);
  }
  // epilogue: C/D map col=lane&15, row=(lane>>4)*4+reg  [m89-verified]
#pragma unroll
  for (int mi = 0; mi < MREP; mi++)
#pragma unroll
    for (int nj = 0; nj < 4; nj++)
#pragma unroll
      for (int r = 0; r < 4; r++) {
        int mm = m0 + wr + mi * 16 + (l >> 4) * 4 + r;
        int nn = n0 + wc + nj * 16 + (l & 15);
        if (nn < Nreal) {
          float v = acc[mi][nj][r];
          if (res) v += res[(size_t)mm * Nreal + nn];
          C[(size_t)mm * Nreal + nn] = v;
        }
      }
}

// ---------------- causal depthwise conv4 + bias + SiLU ----------------------
__global__ void conv_silu_kernel(const float* __restrict__ zx,
                                 const float* __restrict__ cw,
                                 const float* __restrict__ cb,
                                 float* __restrict__ xbc) {
  int idx = blockIdx.x * 256 + threadIdx.x;
  if (idx >= SEQ * CONV_DIM) return;
  int t = idx / CONV_DIM, c = idx % CONV_DIM;
  float acc = cb[c];
#pragma unroll
  for (int k = 0; k < D_CONV; k++) {
    int tt = t + k - (D_CONV - 1);
    if (tt >= 0) acc += zx[(size_t)tt * D_IN_PROJ + D_INNER + c] * cw[c * D_CONV + k];
  }
  xbc[idx] = silu_f(acc);
}

// ---------------- dt = softplus(dt_raw + bias); dA = exp(-exp(A_log)*dt) ----
__global__ void dt_kernel(const float* __restrict__ zx,
                          const float* __restrict__ dtb,
                          const float* __restrict__ Alog,
                          float* __restrict__ dts, float* __restrict__ dab) {
  int idx = blockIdx.x * 256 + threadIdx.x;
  if (idx >= SEQ * NHEADS) return;
  int t = idx / NHEADS, hh = idx % NHEADS;
  float xv = zx[(size_t)t * D_IN_PROJ + 2 * D_INNER + 2 * D_STATE + hh] + dtb[hh];
  float sp = (xv > 20.f) ? xv : log1pf(expf(xv));
  dts[idx] = sp;
  dab[idx] = expf(-expf(Alog[hh]) * sp);
}

// ---------------- scan pass 1: per-(chunk,head) local scan from zero --------
__global__ __launch_bounds__(64) void scan1_kernel(const float* __restrict__ xbc,
                                                   const float* __restrict__ dts,
                                                   const float* __restrict__ dab,
                                                   float* __restrict__ ylocal,
                                                   float* __restrict__ cumdA,
                                                   float* __restrict__ Sbuf) {
  int c = blockIdx.x / NHEADS;
  int hh = blockIdx.x % NHEADS;
  int p = threadIdx.x;
  float hst[64];
#pragma unroll
  for (int i = 0; i < 64; i++) hst[i] = 0.f;
  float cd = 1.f;
  int t0 = c * CHUNK;
  for (int tt = 0; tt < CHUNK; ++tt) {
    int t = t0 + tt;
    float dAv = dab[t * NHEADS + hh];
    float dtp = dts[t * NHEADS + hh] * xbc[(size_t)t * CONV_DIM + hh * 64 + p];
    cd *= dAv;
    if (p == 0) cumdA[t * NHEADS + hh] = cd;
    float y = 0.f;
    const float4* Bv4 = (const float4*)(xbc + (size_t)t * CONV_DIM + D_INNER);
    const float4* Cv4 = (const float4*)(xbc + (size_t)t * CONV_DIM + D_INNER + D_STATE);
#pragma unroll
    for (int sb = 0; sb < 16; ++sb) {
      float4 Bv = Bv4[sb];
      float4 Cv = Cv4[sb];
      hst[4 * sb + 0] = hst[4 * sb + 0] * dAv + dtp * Bv.x;  y += hst[4 * sb + 0] * Cv.x;
      hst[4 * sb + 1] = hst[4 * sb + 1] * dAv + dtp * Bv.y;  y += hst[4 * sb + 1] * Cv.y;
      hst[4 * sb + 2] = hst[4 * sb + 2] * dAv + dtp * Bv.z;  y += hst[4 * sb + 2] * Cv.z;
      hst[4 * sb + 3] = hst[4 * sb + 3] * dAv + dtp * Bv.w;  y += hst[4 * sb + 3] * Cv.w;
    }
    ylocal[(size_t)t * D_INNER + hh * 64 + p] = y;
  }
  float* Sp = Sbuf + (((size_t)c * NHEADS + hh) * 64 + p) * 64;
#pragma unroll
  for (int sb = 0; sb < 16; ++sb)
    *(float4*)(Sp + 4 * sb) =
        make_float4(hst[4 * sb], hst[4 * sb + 1], hst[4 * sb + 2], hst[4 * sb + 3]);
}

// ---------------- scan pass 2: sequential chunk combine (S -> h_start) ------
__global__ __launch_bounds__(64) void scan2_kernel(float* __restrict__ Sbuf,
                                                   const float* __restrict__ cumdA) {
  int hh = blockIdx.x;
  int p = threadIdx.x;
  float run[64];
#pragma unroll
  for (int i = 0; i < 64; i++) run[i] = 0.f;
  for (int c = 0; c < NCHUNK; c++) {
    float P = cumdA[(c * CHUNK + CHUNK - 1) * NHEADS + hh];
    float* Sp = Sbuf + (((size_t)c * NHEADS + hh) * 64 + p) * 64;
#pragma unroll
    for (int sb = 0; sb < 16; sb++) {
      float4 S = *(float4*)(Sp + 4 * sb);
      *(float4*)(Sp + 4 * sb) =
          make_float4(run[4 * sb], run[4 * sb + 1], run[4 * sb + 2], run[4 * sb + 3]);
      run[4 * sb + 0] = P * run[4 * sb + 0] + S.x;
      run[4 * sb + 1] = P * run[4 * sb + 1] + S.y;
      run[4 * sb + 2] = P * run[4 * sb + 2] + S.z;
      run[4 * sb + 3] = P * run[4 * sb + 3] + S.w;
    }
  }
}

// ---- pass 3 per (chunk,head): y = ylocal + cumdA*(h_start . C) + D*xs, gate
__global__ __launch_bounds__(256) void chunk_finish_kernel(
    const float* __restrict__ xbc, const float* __restrict__ zx,
    const float* __restrict__ cumdA, const float* __restrict__ Sbuf,
    const float* __restrict__ Dsk, float* __restrict__ g /*in: ylocal*/) {
  __shared__ float Cs[CHUNK][D_STATE];  // [t][s] broadcast-read
  int b = blockIdx.x;
  int c = b / NHEADS, hh = b % NHEADS;
  int tid = threadIdx.x;
  int p = tid & 63, tq = tid >> 6;
  int t0g = c * CHUNK;
#pragma unroll
  for (int rep = 0; rep < 16; rep++) {
    int idx = rep * 256 + tid;
    int tt = idx >> 6, s = idx & 63;
    Cs[tt][s] = xbc[(size_t)(t0g + tt) * CONV_DIM + D_INNER + D_STATE + s];
  }
  float Hp[64];
  const float* hs = Sbuf + (((size_t)c * NHEADS + hh) * 64 + p) * 64;
#pragma unroll
  for (int sb = 0; sb < 16; sb++) {
    float4 v = *(const float4*)(hs + 4 * sb);
    Hp[4 * sb] = v.x; Hp[4 * sb + 1] = v.y; Hp[4 * sb + 2] = v.z; Hp[4 * sb + 3] = v.w;
  }
  float Dv = Dsk[hh];
  __syncthreads();
#pragma unroll
  for (int it = 0; it < 16; it++) {
    int tt = tq * 16 + it;
    int t = t0g + tt;
    float dot = 0.f;
#pragma unroll
    for (int sb = 0; sb < 16; sb++) {
      float4 cv = *(const float4*)&Cs[tt][4 * sb];
      dot += Hp[4 * sb] * cv.x + Hp[4 * sb + 1] * cv.y +
             Hp[4 * sb + 2] * cv.z + Hp[4 * sb + 3] * cv.w;
    }
    size_t gi = (size_t)t * D_INNER + hh * 64 + p;
    float y = g[gi] + cumdA[t * NHEADS + hh] * dot +
              Dv * xbc[(size_t)t * CONV_DIM + hh * 64 + p];
    float z = zx[(size_t)t * D_IN_PROJ + hh * 64 + p];
    g[gi] = y * silu_f(z);
  }
}

// ---------------- RMSNorm over D_INNER, writes bf16 -------------------------
__global__ __launch_bounds__(256) void rmsnorm_bf_kernel(const float* __restrict__ g,
                                                         const float* __restrict__ nw,
                                                         short* __restrict__ ybn) {
  __shared__ float red[8];
  int t = blockIdx.x;
  const float* gr = g + (size_t)t * D_INNER;
  float v[6];
  float ss = 0.f;
#pragma unroll
  for (int k = 0; k < 6; k++) {
    v[k] = gr[threadIdx.x + k * 256];
    ss += v[k] * v[k];
  }
  ss = block_sum256(ss, red);
  float rs = rsqrtf(ss * (1.f / (float)D_INNER) + EPS);
  short* orow = ybn + (size_t)t * D_INNER;
#pragma unroll
  for (int k = 0; k < 6; k++) {
    int i = threadIdx.x + k * 256;
    orow[i] = f2bf(v[k] * rs * nw[i]);
  }
}

// ---------------- GLU: g = f[:, :H] * silu(f[:, H:2H]) -> bf16 --------------
__global__ void glu_kernel(const float* __restrict__ f, short* __restrict__ g) {
  int idx = blockIdx.x * 256 + threadIdx.x;
  if (idx >= SEQ * HIDDEN) return;
  int t = idx / HIDDEN, i = idx % HIDDEN;
  float a = f[(size_t)t * 2 * HIDDEN + i];
  float b = f[(size_t)t * 2 * HIDDEN + HIDDEN + i];
  g[idx] = f2bf(a * silu_f(b));
}

// ----------------------------------------------------------------------------
extern "C" void kernel_launch(void* const* d_in, const int* in_sizes, int n_in,
                              void* d_out, int out_size, void* d_ws, size_t ws_size,
                              hipStream_t stream) {
  const float* x     = (const float*)d_in[0];
  const float* ln1w  = (const float*)d_in[1];
  const float* ln1b  = (const float*)d_in[2];
  const float* ln2w  = (const float*)d_in[3];
  const float* ln2b  = (const float*)d_in[4];
  const float* Win   = (const float*)d_in[5];
  const float* convw = (const float*)d_in[6];
  const float* convb = (const float*)d_in[7];
  const float* dtb   = (const float*)d_in[8];
  const float* Alog  = (const float*)d_in[9];
  const float* Dsk   = (const float*)d_in[10];
  const float* nrmw  = (const float*)d_in[11];
  const float* Wout  = (const float*)d_in[12];
  const float* Wfc1  = (const float*)d_in[13];
  const float* Wfc2  = (const float*)d_in[14];
  float* out = (float*)d_out;
  float* ws  = (float*)d_ws;

  // ---- workspace layout (float offsets; total 76.4 MB) ----
  float* zx  = ws;                       // 6,602,752 f (also reused for fc1 out f)
  float* xbc = zx + 6602752;             // 3,407,872 f (later reused: g_bf shorts)
  float* ylg = xbc + 3407872;            // 3,145,728 f  ylocal -> g (in place)
  float* Sb  = ylg + 3145728;            // 3,145,728 f  (later: x1 + ybn)
  float* dts = Sb + 3145728;             // 49,152 f
  float* dab = dts + 49152;              // 49,152 f
  float* cda = dab + 49152;              // 49,152 f
  short* hbf = (short*)(cda + 49152);    // 1,572,864 sh
  short* WA  = hbf + 1572864;            // 2,555,904 sh (Win pad 3328x768 / Wfc1)
  short* WB  = WA + 2555904;             // 1,179,648 sh (Wout / Wfc2)

  float* f    = zx;                      // fc1 output 2048x3072 (zx dead)
  short* gbf  = (short*)xbc;             // GLU output bf16 (xbc dead)
  float* x1   = Sb;                      // 1,572,864 f (Sb dead after chunk_finish)
  short* ybn  = (short*)(Sb + 1572864);  // 3,145,728 sh (fits in Sb 2nd half)

  // 1) cast in_proj weight (padded 3224->3328 rows)
  castpad_kernel<<<(3328 * 768 + 255) / 256, 256, 0, stream>>>(Win, WA, 3328 * 768, 3224 * 768);
  // 2) LN1 -> bf16
  ln_kernel<<<SEQ, 256, 0, stream>>>(x, ln1w, ln1b, hbf);
  // 3) in_proj: zx = h @ Win^T  (2048 x 3224, K=768)
  mfma_gemm_bt<4><<<dim3(26, 16), 256, 0, stream>>>(hbf, WA, zx, nullptr, SEQ, D_IN_PROJ, D_MODEL);
  // 4) conv + silu
  conv_silu_kernel<<<(SEQ * CONV_DIM + 255) / 256, 256, 0, stream>>>(zx, convw, convb, xbc);
  // 5) dt / dA
  dt_kernel<<<(SEQ * NHEADS + 255) / 256, 256, 0, stream>>>(zx, dtb, Alog, dts, dab);
  // 6) chunked scan
  scan1_kernel<<<NCHUNK * NHEADS, 64, 0, stream>>>(xbc, dts, dab, ylg, cda, Sb);
  scan2_kernel<<<NHEADS, 64, 0, stream>>>(Sb, cda);
  chunk_finish_kernel<<<NCHUNK * NHEADS, 256, 0, stream>>>(xbc, zx, cda, Sb, Dsk, ylg);
  // 7) RMSNorm -> bf16
  rmsnorm_bf_kernel<<<SEQ, 256, 0, stream>>>(ylg, nrmw, ybn);
  // 8) out_proj + residual: x1 = x + y @ Wout^T  (N=768, K=1536)
  castpad_kernel<<<(768 * 1536 + 255) / 256, 256, 0, stream>>>(Wout, WB, 768 * 1536, 768 * 1536);
  mfma_gemm_bt<2><<<dim3(6, 32), 256, 0, stream>>>(ybn, WB, x1, x, SEQ, D_MODEL, D_INNER);
  // 9) LN2 -> bf16
  ln_kernel<<<SEQ, 256, 0, stream>>>(x1, ln2w, ln2b, hbf);
  // 10) fc1: f = h @ Wfc1^T (N=3072, K=768)
  castpad_kernel<<<(3072 * 768 + 255) / 256, 256, 0, stream>>>(Wfc1, WA, 3072 * 768, 3072 * 768);
  mfma_gemm_bt<4><<<dim3(24, 16), 256, 0, stream>>>(hbf, WA, f, nullptr, SEQ, 2 * HIDDEN, D_MODEL);
  // 11) GLU -> bf16
  glu_kernel<<<(SEQ * HIDDEN + 255) / 256, 256, 0, stream>>>(f, gbf);
  // 12) fc2 + residual: out = x1 + g @ Wfc2^T (N=768, K=1536)
  castpad_kernel<<<(768 * 1536 + 255) / 256, 256, 0, stream>>>(Wfc2, WB, 768 * 1536, 768 * 1536);
  mfma_gemm_bt<2><<<dim3(6, 32), 256, 0, stream>>>(gbf, WB, out, x1, SEQ, D_MODEL, HIDDEN);
}

// Round 3
// 298.254 us; speedup vs baseline: 2.7164x; 1.1509x over previous
//
#include <hip/hip_runtime.h>
#include <math.h>

#define D_MODEL 768
#define SEQ 2048
#define D_STATE 64
#define D_CONV 4
#define D_INNER 1536
#define HEADDIM 64
#define NHEADS 24
#define CONV_DIM 1664      // D_INNER + 2*D_STATE
#define D_IN_PROJ 3224     // 2*D_INNER + 2*D_STATE + NHEADS
#define HIDDEN 1536
#define EPS 1e-5f
#define NCHUNK 32
#define CHUNK 64

typedef short s16x8 __attribute__((ext_vector_type(8)));
typedef float f32x4 __attribute__((ext_vector_type(4)));

// ---------------- helpers ---------------------------------------------------
__device__ __forceinline__ float silu_f(float x) { return x / (1.f + expf(-x)); }

__device__ __forceinline__ short f2bf(float x) {  // RNE fp32 -> bf16 bits
  unsigned u = __builtin_bit_cast(unsigned, x);
  unsigned r = (u + 0x7fffu + ((u >> 16) & 1u)) >> 16;
  return (short)r;
}

__device__ __forceinline__ float block_sum256(float v, float* sdata) {
#pragma unroll
  for (int o = 32; o > 0; o >>= 1) v += __shfl_down(v, o);
  int lane = threadIdx.x & 63, wid = threadIdx.x >> 6;
  __syncthreads();
  if (lane == 0) sdata[wid] = v;
  __syncthreads();
  if (threadIdx.x == 0) sdata[0] = sdata[0] + sdata[1] + sdata[2] + sdata[3];
  __syncthreads();
  return sdata[0];
}

// async 16B global->LDS (linear dest: wave-uniform base + lane*16)
__device__ __forceinline__ void gll16(const short* gsrc, const short* ldst) {
  __builtin_amdgcn_global_load_lds(
      (const __attribute__((address_space(1))) unsigned int*)(unsigned long long)gsrc,
      (__attribute__((address_space(3))) unsigned int*)(unsigned int)(unsigned long long)ldst,
      16, 0, 0);
}

// ---------------- LayerNorm over 768, writes bf16 ---------------------------
__global__ __launch_bounds__(256) void ln_kernel(const float* __restrict__ x,
                                                 const float* __restrict__ w,
                                                 const float* __restrict__ b,
                                                 short* __restrict__ out) {
  __shared__ float red[8];
  int row = blockIdx.x;
  const float* xr = x + (size_t)row * D_MODEL;
  float v[3];
#pragma unroll
  for (int k = 0; k < 3; k++) v[k] = xr[threadIdx.x + k * 256];
  float s = v[0] + v[1] + v[2];
  s = block_sum256(s, red);
  float mean = s * (1.f / 768.f);
  float q = 0.f;
#pragma unroll
  for (int k = 0; k < 3; k++) { float d = v[k] - mean; q += d * d; }
  q = block_sum256(q, red);
  float rstd = rsqrtf(q * (1.f / 768.f) + EPS);
  short* orow = out + (size_t)row * D_MODEL;
#pragma unroll
  for (int k = 0; k < 3; k++) {
    int i = threadIdx.x + k * 256;
    orow[i] = f2bf((v[k] - mean) * rstd * w[i] + b[i]);
  }
}

// ---------------- weight cast fp32 -> bf16 with row padding -----------------
__global__ void castpad_kernel(const float* __restrict__ src, short* __restrict__ dst,
                               int total, int realtotal) {
  int idx = blockIdx.x * 256 + threadIdx.x;
  if (idx >= total) return;
  dst[idx] = (idx < realtotal) ? f2bf(src[idx]) : (short)0;
}

// ---------------- bf16 MFMA GEMM: C = A(MxK) * W(NpadxK)^T (+res) -----------
// MREP=4 -> 128x128 tile; MREP=2 -> 64x128 tile. 256 threads = 4 waves (2x2).
template <int MREP>
__global__ __launch_bounds__(256) void mfma_gemm_bt(const short* __restrict__ A,
                                                    const short* __restrict__ Bw,
                                                    float* __restrict__ C,
                                                    const float* __restrict__ res,
                                                    int M, int Nreal, int K) {
  constexpr int BMr = MREP * 32;
  __shared__ short As[BMr * 32];
  __shared__ short Bs[128 * 32];
  int tid = threadIdx.x, w = tid >> 6, l = tid & 63;
  int m0 = blockIdx.y * BMr, n0 = blockIdx.x * 128;
  int wr = (w >> 1) * (MREP * 16), wc = (w & 1) * 64;
  f32x4 acc[MREP][4] = {};

  for (int kt = 0; kt < K; kt += 32) {
    __syncthreads();
    // stage A tile (BMr x 32 bf16), LDS linear, global source slot-swizzled
#pragma unroll
    for (int q = 0; q < BMr / 64; q++) {
      int chunk = w * (BMr / 64) + q;      // 16-row chunk
      int row = chunk * 16 + (l >> 2);
      int gs = (l & 3) ^ (row & 3);
      gll16(A + (size_t)(m0 + row) * K + kt + gs * 8, As + chunk * 512);
    }
    // stage B tile (128 x 32 bf16)
#pragma unroll
    for (int q = 0; q < 2; q++) {
      int chunk = w * 2 + q;
      int row = chunk * 16 + (l >> 2);
      int gs = (l & 3) ^ (row & 3);
      gll16(Bw + (size_t)(n0 + row) * K + kt + gs * 8, Bs + chunk * 512);
    }
    __syncthreads();
    s16x8 af[MREP], bfr[4];
#pragma unroll
    for (int mi = 0; mi < MREP; mi++) {
      int row = wr + mi * 16 + (l & 15);
      int sl = (l >> 4) ^ (row & 3);
      af[mi] = *(const s16x8*)&As[row * 32 + sl * 8];
    }
#pragma unroll
    for (int nj = 0; nj < 4; nj++) {
      int row = wc + nj * 16 + (l & 15);
      int sl = (l >> 4) ^ (row & 3);
      bfr[nj] = *(const s16x8*)&Bs[row * 32 + sl * 8];
    }
#pragma unroll
    for (int mi = 0; mi < MREP; mi++)
#pragma unroll
      for (int nj = 0; nj < 4; nj++)
        acc[mi][nj] = __builtin_amdgcn_mfma_f32_16x16x32_bf16(af[mi], bfr[nj],
                                                              acc[mi][nj], 0, 0, 0);
  }
  // epilogue: C/D map col=lane&15, row=(lane>>4)*4+reg  [m89-verified]
#pragma unroll
  for (int mi = 0; mi < MREP; mi++)
#pragma unroll
    for (int nj = 0; nj < 4; nj++)
#pragma unroll
      for (int r = 0; r < 4; r++) {
        int mm = m0 + wr + mi * 16 + (l >> 4) * 4 + r;
        int nn = n0 + wc + nj * 16 + (l & 15);
        if (nn < Nreal) {
          float v = acc[mi][nj][r];
          if (res) v += res[(size_t)mm * Nreal + nn];
          C[(size_t)mm * Nreal + nn] = v;
        }
      }
}

// ---------------- causal depthwise conv4 + bias + SiLU ----------------------
__global__ void conv_silu_kernel(const float* __restrict__ zx,
                                 const float* __restrict__ cw,
                                 const float* __restrict__ cb,
                                 float* __restrict__ xbc) {
  int idx = blockIdx.x * 256 + threadIdx.x;
  if (idx >= SEQ * CONV_DIM) return;
  int t = idx / CONV_DIM, c = idx % CONV_DIM;
  float acc = cb[c];
#pragma unroll
  for (int k = 0; k < D_CONV; k++) {
    int tt = t + k - (D_CONV - 1);
    if (tt >= 0) acc += zx[(size_t)tt * D_IN_PROJ + D_INNER + c] * cw[c * D_CONV + k];
  }
  xbc[idx] = silu_f(acc);
}

// ---------------- dt = softplus(dt_raw + bias); dA = exp(-exp(A_log)*dt) ----
__global__ void dt_kernel(const float* __restrict__ zx,
                          const float* __restrict__ dtb,
                          const float* __restrict__ Alog,
                          float* __restrict__ dts, float* __restrict__ dab) {
  int idx = blockIdx.x * 256 + threadIdx.x;
  if (idx >= SEQ * NHEADS) return;
  int t = idx / NHEADS, hh = idx % NHEADS;
  float xv = zx[(size_t)t * D_IN_PROJ + 2 * D_INNER + 2 * D_STATE + hh] + dtb[hh];
  float sp = (xv > 20.f) ? xv : log1pf(expf(xv));
  dts[idx] = sp;
  dab[idx] = expf(-expf(Alog[hh]) * sp);
}

// ---- scan pass 1: per-(chunk,head) local scan, 256 thr, 16 states/thread ---
// thread (p=tid>>2, sq=tid&3) owns states sq*16..sq*16+15 of row p.
__global__ __launch_bounds__(256) void scan1_kernel(const float* __restrict__ xbc,
                                                    const float* __restrict__ dts,
                                                    const float* __restrict__ dab,
                                                    float* __restrict__ ylocal,
                                                    float* __restrict__ cumdA,
                                                    float* __restrict__ Sbuf) {
  int c = blockIdx.x / NHEADS;
  int hh = blockIdx.x % NHEADS;
  int tid = threadIdx.x;
  int p = tid >> 2, sq = tid & 3;
  const float* base = xbc + (size_t)(c * CHUNK) * CONV_DIM;
  float hst[16];
#pragma unroll
  for (int i = 0; i < 16; i++) hst[i] = 0.f;
  float cd = 1.f;
  float4 Bc[4], Cc[4];
  float xsc, dAc, dtc;
  {
    const float* r = base;
#pragma unroll
    for (int q = 0; q < 4; q++) {
      Bc[q] = *(const float4*)(r + D_INNER + sq * 16 + q * 4);
      Cc[q] = *(const float4*)(r + D_INNER + D_STATE + sq * 16 + q * 4);
    }
    xsc = r[hh * 64 + p];
    dAc = dab[(c * CHUNK) * NHEADS + hh];
    dtc = dts[(c * CHUNK) * NHEADS + hh];
  }
  for (int tt = 0; tt < CHUNK; ++tt) {
    // prefetch t+1 while computing t
    float4 Bn[4], Cn[4];
    float xsn = 0.f, dAn = 0.f, dtn = 0.f;
    if (tt + 1 < CHUNK) {
      const float* r = base + (size_t)(tt + 1) * CONV_DIM;
#pragma unroll
      for (int q = 0; q < 4; q++) {
        Bn[q] = *(const float4*)(r + D_INNER + sq * 16 + q * 4);
        Cn[q] = *(const float4*)(r + D_INNER + D_STATE + sq * 16 + q * 4);
      }
      xsn = r[hh * 64 + p];
      dAn = dab[(c * CHUNK + tt + 1) * NHEADS + hh];
      dtn = dts[(c * CHUNK + tt + 1) * NHEADS + hh];
    }
    float dtp = dtc * xsc;
    cd *= dAc;
    int t = c * CHUNK + tt;
    if (tid == 0) cumdA[t * NHEADS + hh] = cd;
    float y0 = 0.f, y1 = 0.f, y2 = 0.f, y3 = 0.f;
#pragma unroll
    for (int q = 0; q < 4; q++) {
      hst[4*q+0] = fmaf(hst[4*q+0], dAc, dtp * Bc[q].x); y0 = fmaf(hst[4*q+0], Cc[q].x, y0);
      hst[4*q+1] = fmaf(hst[4*q+1], dAc, dtp * Bc[q].y); y1 = fmaf(hst[4*q+1], Cc[q].y, y1);
      hst[4*q+2] = fmaf(hst[4*q+2], dAc, dtp * Bc[q].z); y2 = fmaf(hst[4*q+2], Cc[q].z, y2);
      hst[4*q+3] = fmaf(hst[4*q+3], dAc, dtp * Bc[q].w); y3 = fmaf(hst[4*q+3], Cc[q].w, y3);
    }
    float y = (y0 + y1) + (y2 + y3);
    y += __shfl_xor(y, 1);
    y += __shfl_xor(y, 2);
    if (sq == 0) ylocal[(size_t)t * D_INNER + hh * 64 + p] = y;
#pragma unroll
    for (int q = 0; q < 4; q++) { Bc[q] = Bn[q]; Cc[q] = Cn[q]; }
    xsc = xsn; dAc = dAn; dtc = dtn;
  }
  float* Sp = Sbuf + (((size_t)c * NHEADS + hh) * 64 + p) * 64 + sq * 16;
#pragma unroll
  for (int q = 0; q < 4; q++)
    *(float4*)(Sp + q * 4) =
        make_float4(hst[4*q], hst[4*q+1], hst[4*q+2], hst[4*q+3]);
}

// ---- scan pass 2: chunk combine, 1 thread per (hh,p,s) element -------------
__global__ __launch_bounds__(256) void scan2_kernel(float* __restrict__ Sbuf,
                                                    const float* __restrict__ cumdA) {
  int idx = blockIdx.x * 256 + threadIdx.x;   // [0, 24*4096)
  int hh = idx >> 12;           // uniform per block (4096 % 256 == 0)
  int rem = idx & 4095;         // p*64 + s
  float Sv[NCHUNK];
#pragma unroll
  for (int c = 0; c < NCHUNK; c++)
    Sv[c] = Sbuf[((size_t)c * NHEADS + hh) * 4096 + rem];
  float run = 0.f;
#pragma unroll
  for (int c = 0; c < NCHUNK; c++) {
    float P = cumdA[(c * CHUNK + CHUNK - 1) * NHEADS + hh];
    Sbuf[((size_t)c * NHEADS + hh) * 4096 + rem] = run;
    run = fmaf(P, run, Sv[c]);
  }
}

// ---- pass 3 per (chunk,head): y = ylocal + cumdA*(h_start . C) + D*xs, gate
__global__ __launch_bounds__(256) void chunk_finish_kernel(
    const float* __restrict__ xbc, const float* __restrict__ zx,
    const float* __restrict__ cumdA, const float* __restrict__ Sbuf,
    const float* __restrict__ Dsk, float* __restrict__ g /*in: ylocal*/) {
  __shared__ float Cs[CHUNK][D_STATE];  // [t][s] broadcast-read
  int b = blockIdx.x;
  int c = b / NHEADS, hh = b % NHEADS;
  int tid = threadIdx.x;
  int p = tid & 63, tq = tid >> 6;
  int t0g = c * CHUNK;
#pragma unroll
  for (int rep = 0; rep < 16; rep++) {
    int idx = rep * 256 + tid;
    int tt = idx >> 6, s = idx & 63;
    Cs[tt][s] = xbc[(size_t)(t0g + tt) * CONV_DIM + D_INNER + D_STATE + s];
  }
  float Hp[64];
  const float* hs = Sbuf + (((size_t)c * NHEADS + hh) * 64 + p) * 64;
#pragma unroll
  for (int sb = 0; sb < 16; sb++) {
    float4 v = *(const float4*)(hs + 4 * sb);
    Hp[4 * sb] = v.x; Hp[4 * sb + 1] = v.y; Hp[4 * sb + 2] = v.z; Hp[4 * sb + 3] = v.w;
  }
  float Dv = Dsk[hh];
  __syncthreads();
#pragma unroll
  for (int it = 0; it < 16; it++) {
    int tt = tq * 16 + it;
    int t = t0g + tt;
    float dot = 0.f;
#pragma unroll
    for (int sb = 0; sb < 16; sb++) {
      float4 cv = *(const float4*)&Cs[tt][4 * sb];
      dot += Hp[4 * sb] * cv.x + Hp[4 * sb + 1] * cv.y +
             Hp[4 * sb + 2] * cv.z + Hp[4 * sb + 3] * cv.w;
    }
    size_t gi = (size_t)t * D_INNER + hh * 64 + p;
    float y = g[gi] + cumdA[t * NHEADS + hh] * dot +
              Dv * xbc[(size_t)t * CONV_DIM + hh * 64 + p];
    float z = zx[(size_t)t * D_IN_PROJ + hh * 64 + p];
    g[gi] = y * silu_f(z);
  }
}

// ---------------- RMSNorm over D_INNER, writes bf16 -------------------------
__global__ __launch_bounds__(256) void rmsnorm_bf_kernel(const float* __restrict__ g,
                                                         const float* __restrict__ nw,
                                                         short* __restrict__ ybn) {
  __shared__ float red[8];
  int t = blockIdx.x;
  const float* gr = g + (size_t)t * D_INNER;
  float v[6];
  float ss = 0.f;
#pragma unroll
  for (int k = 0; k < 6; k++) {
    v[k] = gr[threadIdx.x + k * 256];
    ss += v[k] * v[k];
  }
  ss = block_sum256(ss, red);
  float rs = rsqrtf(ss * (1.f / (float)D_INNER) + EPS);
  short* orow = ybn + (size_t)t * D_INNER;
#pragma unroll
  for (int k = 0; k < 6; k++) {
    int i = threadIdx.x + k * 256;
    orow[i] = f2bf(v[k] * rs * nw[i]);
  }
}

// ---------------- GLU: g = f[:, :H] * silu(f[:, H:2H]) -> bf16 --------------
__global__ void glu_kernel(const float* __restrict__ f, short* __restrict__ g) {
  int idx = blockIdx.x * 256 + threadIdx.x;
  if (idx >= SEQ * HIDDEN) return;
  int t = idx / HIDDEN, i = idx % HIDDEN;
  float a = f[(size_t)t * 2 * HIDDEN + i];
  float b = f[(size_t)t * 2 * HIDDEN + HIDDEN + i];
  g[idx] = f2bf(a * silu_f(b));
}

// ----------------------------------------------------------------------------
extern "C" void kernel_launch(void* const* d_in, const int* in_sizes, int n_in,
                              void* d_out, int out_size, void* d_ws, size_t ws_size,
                              hipStream_t stream) {
  const float* x     = (const float*)d_in[0];
  const float* ln1w  = (const float*)d_in[1];
  const float* ln1b  = (const float*)d_in[2];
  const float* ln2w  = (const float*)d_in[3];
  const float* ln2b  = (const float*)d_in[4];
  const float* Win   = (const float*)d_in[5];
  const float* convw = (const float*)d_in[6];
  const float* convb = (const float*)d_in[7];
  const float* dtb   = (const float*)d_in[8];
  const float* Alog  = (const float*)d_in[9];
  const float* Dsk   = (const float*)d_in[10];
  const float* nrmw  = (const float*)d_in[11];
  const float* Wout  = (const float*)d_in[12];
  const float* Wfc1  = (const float*)d_in[13];
  const float* Wfc2  = (const float*)d_in[14];
  float* out = (float*)d_out;
  float* ws  = (float*)d_ws;

  // ---- workspace layout (float offsets; total 76.4 MB) ----
  float* zx  = ws;                       // 6,602,752 f (also reused for fc1 out f)
  float* xbc = zx + 6602752;             // 3,407,872 f (later reused: g_bf shorts)
  float* ylg = xbc + 3407872;            // 3,145,728 f  ylocal -> g (in place)
  float* Sb  = ylg + 3145728;            // 3,145,728 f  (later: x1 + ybn)
  float* dts = Sb + 3145728;             // 49,152 f
  float* dab = dts + 49152;              // 49,152 f
  float* cda = dab + 49152;              // 49,152 f
  short* hbf = (short*)(cda + 49152);    // 1,572,864 sh
  short* WA  = hbf + 1572864;            // 2,555,904 sh (Win pad 3328x768 / Wfc1)
  short* WB  = WA + 2555904;             // 1,179,648 sh (Wout / Wfc2)

  float* f    = zx;                      // fc1 output 2048x3072 (zx dead)
  short* gbf  = (short*)xbc;             // GLU output bf16 (xbc dead)
  float* x1   = Sb;                      // 1,572,864 f (Sb dead after chunk_finish)
  short* ybn  = (short*)(Sb + 1572864);  // 3,145,728 sh (fits in Sb 2nd half)

  // 1) cast in_proj weight (padded 3224->3328 rows)
  castpad_kernel<<<(3328 * 768 + 255) / 256, 256, 0, stream>>>(Win, WA, 3328 * 768, 3224 * 768);
  // 2) LN1 -> bf16
  ln_kernel<<<SEQ, 256, 0, stream>>>(x, ln1w, ln1b, hbf);
  // 3) in_proj: zx = h @ Win^T  (2048 x 3224, K=768)
  mfma_gemm_bt<4><<<dim3(26, 16), 256, 0, stream>>>(hbf, WA, zx, nullptr, SEQ, D_IN_PROJ, D_MODEL);
  // 4) conv + silu
  conv_silu_kernel<<<(SEQ * CONV_DIM + 255) / 256, 256, 0, stream>>>(zx, convw, convb, xbc);
  // 5) dt / dA
  dt_kernel<<<(SEQ * NHEADS + 255) / 256, 256, 0, stream>>>(zx, dtb, Alog, dts, dab);
  // 6) chunked scan
  scan1_kernel<<<NCHUNK * NHEADS, 256, 0, stream>>>(xbc, dts, dab, ylg, cda, Sb);
  scan2_kernel<<<(NHEADS * 4096) / 256, 256, 0, stream>>>(Sb, cda);
  chunk_finish_kernel<<<NCHUNK * NHEADS, 256, 0, stream>>>(xbc, zx, cda, Sb, Dsk, ylg);
  // 7) RMSNorm -> bf16
  rmsnorm_bf_kernel<<<SEQ, 256, 0, stream>>>(ylg, nrmw, ybn);
  // 8) out_proj + residual: x1 = x + y @ Wout^T  (N=768, K=1536)
  castpad_kernel<<<(768 * 1536 + 255) / 256, 256, 0, stream>>>(Wout, WB, 768 * 1536, 768 * 1536);
  mfma_gemm_bt<2><<<dim3(6, 32), 256, 0, stream>>>(ybn, WB, x1, x, SEQ, D_MODEL, D_INNER);
  // 9) LN2 -> bf16
  ln_kernel<<<SEQ, 256, 0, stream>>>(x1, ln2w, ln2b, hbf);
  // 10) fc1: f = h @ Wfc1^T (N=3072, K=768)
  castpad_kernel<<<(3072 * 768 + 255) / 256, 256, 0, stream>>>(Wfc1, WA, 3072 * 768, 3072 * 768);
  mfma_gemm_bt<4><<<dim3(24, 16), 256, 0, stream>>>(hbf, WA, f, nullptr, SEQ, 2 * HIDDEN, D_MODEL);
  // 11) GLU -> bf16
  glu_kernel<<<(SEQ * HIDDEN + 255) / 256, 256, 0, stream>>>(f, gbf);
  // 12) fc2 + residual: out = x1 + g @ Wfc2^T (N=768, K=1536)
  castpad_kernel<<<(768 * 1536 + 255) / 256, 256, 0, stream>>>(Wfc2, WB, 768 * 1536, 768 * 1536);
  mfma_gemm_bt<2><<<dim3(6, 32), 256, 0, stream>>>(gbf, WB, out, x1, SEQ, D_MODEL, HIDDEN);
}

// Round 4
// 220.235 us; speedup vs baseline: 3.6788x; 1.3543x over previous
//
#include <hip/hip_runtime.h>
#include <math.h>

#define D_MODEL 768
#define SEQ 2048
#define D_STATE 64
#define D_CONV 4
#define D_INNER 1536
#define HEADDIM 64
#define NHEADS 24
#define CONV_DIM 1664      // D_INNER + 2*D_STATE
#define D_IN_PROJ 3224     // 2*D_INNER + 2*D_STATE + NHEADS
#define HIDDEN 1536
#define EPS 1e-5f
#define NCHUNK 32
#define CHUNK 64

typedef short s16x8 __attribute__((ext_vector_type(8)));
typedef float f32x4 __attribute__((ext_vector_type(4)));

// XOR-swizzled 64x64 bf16 tile accessor: row-stride 64 shorts, 8-short slots,
// slot ^= (row&7). Conflict-free-ish b128 frag reads; involution (self-inverse).
#define SWZ(row, k) (((row) << 6) + ((((k) >> 3) ^ ((row) & 7)) << 3) + ((k) & 7))

// ---------------- helpers ---------------------------------------------------
__device__ __forceinline__ float silu_f(float x) { return x / (1.f + expf(-x)); }

__device__ __forceinline__ short f2bf(float x) {  // RNE fp32 -> bf16 bits
  unsigned u = __builtin_bit_cast(unsigned, x);
  unsigned r = (u + 0x7fffu + ((u >> 16) & 1u)) >> 16;
  return (short)r;
}
__device__ __forceinline__ float bf2f(short s) {
  unsigned u = ((unsigned)(unsigned short)s) << 16;
  return __builtin_bit_cast(float, u);
}

__device__ __forceinline__ float block_sum256(float v, float* sdata) {
#pragma unroll
  for (int o = 32; o > 0; o >>= 1) v += __shfl_down(v, o);
  int lane = threadIdx.x & 63, wid = threadIdx.x >> 6;
  __syncthreads();
  if (lane == 0) sdata[wid] = v;
  __syncthreads();
  if (threadIdx.x == 0) sdata[0] = sdata[0] + sdata[1] + sdata[2] + sdata[3];
  __syncthreads();
  return sdata[0];
}

// async 16B global->LDS (dest: wave-uniform base + lane*16)
__device__ __forceinline__ void gll16(const short* gsrc, const short* ldst) {
  __builtin_amdgcn_global_load_lds(
      (const __attribute__((address_space(1))) unsigned int*)(unsigned long long)gsrc,
      (__attribute__((address_space(3))) unsigned int*)(unsigned int)(unsigned long long)ldst,
      16, 0, 0);
}

// ---------------- LayerNorm over 768, writes bf16 ---------------------------
__global__ __launch_bounds__(256) void ln_kernel(const float* __restrict__ x,
                                                 const float* __restrict__ w,
                                                 const float* __restrict__ b,
                                                 short* __restrict__ out) {
  __shared__ float red[8];
  int row = blockIdx.x;
  const float* xr = x + (size_t)row * D_MODEL;
  float v[3];
#pragma unroll
  for (int k = 0; k < 3; k++) v[k] = xr[threadIdx.x + k * 256];
  float s = v[0] + v[1] + v[2];
  s = block_sum256(s, red);
  float mean = s * (1.f / 768.f);
  float q = 0.f;
#pragma unroll
  for (int k = 0; k < 3; k++) { float d = v[k] - mean; q += d * d; }
  q = block_sum256(q, red);
  float rstd = rsqrtf(q * (1.f / 768.f) + EPS);
  short* orow = out + (size_t)row * D_MODEL;
#pragma unroll
  for (int k = 0; k < 3; k++) {
    int i = threadIdx.x + k * 256;
    orow[i] = f2bf((v[k] - mean) * rstd * w[i] + b[i]);
  }
}

// ---------------- weight cast fp32 -> bf16 with row padding -----------------
__global__ void castpad_kernel(const float* __restrict__ src, short* __restrict__ dst,
                               int total, int realtotal) {
  int idx = blockIdx.x * 256 + threadIdx.x;
  if (idx >= total) return;
  dst[idx] = (idx < realtotal) ? f2bf(src[idx]) : (short)0;
}

// ---------------- bf16 MFMA GEMM: C = A(MxK) * W(NpadxK)^T (+res) -----------
template <int MREP>
__global__ __launch_bounds__(256) void mfma_gemm_bt(const short* __restrict__ A,
                                                    const short* __restrict__ Bw,
                                                    float* __restrict__ C,
                                                    const float* __restrict__ res,
                                                    int M, int Nreal, int K) {
  constexpr int BMr = MREP * 32;
  __shared__ short As[BMr * 32];
  __shared__ short Bs[128 * 32];
  int tid = threadIdx.x, w = tid >> 6, l = tid & 63;
  int m0 = blockIdx.y * BMr, n0 = blockIdx.x * 128;
  int wr = (w >> 1) * (MREP * 16), wc = (w & 1) * 64;
  f32x4 acc[MREP][4] = {};

  for (int kt = 0; kt < K; kt += 32) {
    __syncthreads();
#pragma unroll
    for (int q = 0; q < BMr / 64; q++) {
      int chunk = w * (BMr / 64) + q;
      int row = chunk * 16 + (l >> 2);
      int gs = (l & 3) ^ (row & 3);
      gll16(A + (size_t)(m0 + row) * K + kt + gs * 8, As + chunk * 512);
    }
#pragma unroll
    for (int q = 0; q < 2; q++) {
      int chunk = w * 2 + q;
      int row = chunk * 16 + (l >> 2);
      int gs = (l & 3) ^ (row & 3);
      gll16(Bw + (size_t)(n0 + row) * K + kt + gs * 8, Bs + chunk * 512);
    }
    __syncthreads();
    s16x8 af[MREP], bfr[4];
#pragma unroll
    for (int mi = 0; mi < MREP; mi++) {
      int row = wr + mi * 16 + (l & 15);
      int sl = (l >> 4) ^ (row & 3);
      af[mi] = *(const s16x8*)&As[row * 32 + sl * 8];
    }
#pragma unroll
    for (int nj = 0; nj < 4; nj++) {
      int row = wc + nj * 16 + (l & 15);
      int sl = (l >> 4) ^ (row & 3);
      bfr[nj] = *(const s16x8*)&Bs[row * 32 + sl * 8];
    }
#pragma unroll
    for (int mi = 0; mi < MREP; mi++)
#pragma unroll
      for (int nj = 0; nj < 4; nj++)
        acc[mi][nj] = __builtin_amdgcn_mfma_f32_16x16x32_bf16(af[mi], bfr[nj],
                                                              acc[mi][nj], 0, 0, 0);
  }
#pragma unroll
  for (int mi = 0; mi < MREP; mi++)
#pragma unroll
    for (int nj = 0; nj < 4; nj++)
#pragma unroll
      for (int r = 0; r < 4; r++) {
        int mm = m0 + wr + mi * 16 + (l >> 4) * 4 + r;
        int nn = n0 + wc + nj * 16 + (l & 15);
        if (nn < Nreal) {
          float v = acc[mi][nj][r];
          if (res) v += res[(size_t)mm * Nreal + nn];
          C[(size_t)mm * Nreal + nn] = v;
        }
      }
}

// ---------------- causal depthwise conv4 + bias + SiLU ----------------------
__global__ void conv_silu_kernel(const float* __restrict__ zx,
                                 const float* __restrict__ cw,
                                 const float* __restrict__ cb,
                                 float* __restrict__ xbc) {
  int idx = blockIdx.x * 256 + threadIdx.x;
  if (idx >= SEQ * CONV_DIM) return;
  int t = idx / CONV_DIM, c = idx % CONV_DIM;
  float acc = cb[c];
#pragma unroll
  for (int k = 0; k < D_CONV; k++) {
    int tt = t + k - (D_CONV - 1);
    if (tt >= 0) acc += zx[(size_t)tt * D_IN_PROJ + D_INNER + c] * cw[c * D_CONV + k];
  }
  xbc[idx] = silu_f(acc);
}

// ------- dt = softplus(dt_raw + bias); la <- log dA = -exp(A_log)*dt --------
__global__ void dt_kernel(const float* __restrict__ zx,
                          const float* __restrict__ dtb,
                          const float* __restrict__ Alog,
                          float* __restrict__ dts, float* __restrict__ laB) {
  int idx = blockIdx.x * 256 + threadIdx.x;
  if (idx >= SEQ * NHEADS) return;
  int t = idx / NHEADS, hh = idx % NHEADS;
  float xv = zx[(size_t)t * D_IN_PROJ + 2 * D_INNER + 2 * D_STATE + hh] + dtb[hh];
  float sp = (xv > 20.f) ? xv : log1pf(expf(xv));
  dts[idx] = sp;
  laB[idx] = -expf(Alog[hh]) * sp;
}

// ------- chunk-local inclusive cumsum of log dA (one wave per (c,h)) --------
__global__ __launch_bounds__(256) void la_scan_kernel(float* __restrict__ laB) {
  int W = blockIdx.x * 4 + (threadIdx.x >> 6);  // 0..767
  int c = W / NHEADS, h = W % NHEADS;
  int t = threadIdx.x & 63;
  int gi = (c * CHUNK + t) * NHEADS + h;
  float v = laB[gi];
#pragma unroll
  for (int off = 1; off < 64; off <<= 1) {
    float u = __shfl_up(v, off);
    if (t >= off) v += u;
  }
  laB[gi] = v;
}

// ------- pack xbc into MFMA layouts: XTall (xs^T bf16), BTg (B^T), BCbf -----
__global__ __launch_bounds__(256) void postpack_kernel(const float* __restrict__ xbc,
                                                       short* __restrict__ XTall,
                                                       short* __restrict__ BTg,
                                                       short* __restrict__ BCbf) {
  __shared__ float T[64][65];
  int ct = blockIdx.x, rt = blockIdx.y;
  int lane = threadIdx.x & 63, grp = threadIdx.x >> 6;
#pragma unroll
  for (int j = 0; j < 16; j++) {
    int row = grp * 16 + j;
    float v = xbc[(size_t)(rt * 64 + row) * CONV_DIM + ct * 64 + lane];
    T[row][lane] = v;
    if (ct >= 24)
      BCbf[(size_t)(rt * 64 + row) * 128 + (ct - 24) * 64 + lane] = f2bf(v);
  }
  __syncthreads();
  if (ct < 24) {
#pragma unroll
    for (int j = 0; j < 16; j++) {
      int cc = grp * 16 + j;
      XTall[(size_t)(ct * 64 + cc) * 2048 + rt * 64 + lane] = f2bf(T[lane][cc]);
    }
  } else if (ct == 24) {
#pragma unroll
    for (int j = 0; j < 16; j++) {
      int cc = grp * 16 + j;
      BTg[(size_t)cc * 2048 + rt * 64 + lane] = f2bf(T[lane][cc]);
    }
  }
}

// ------- SSD-A per (chunk,head): G=C@B^T, M, y_diag=M@X, h_end=(wX)^T@B -----
__global__ __launch_bounds__(256) void ssd_a_kernel(const short* __restrict__ BCbf,
                                                    const short* __restrict__ XTall,
                                                    const short* __restrict__ BTg,
                                                    const float* __restrict__ laB,
                                                    const float* __restrict__ dts,
                                                    short* __restrict__ ylg,
                                                    float* __restrict__ Sb) {
  __shared__ short Cl[4096], Bl[4096], XTl[4096], BTl[4096], Ml[4096];
  __shared__ float la_s[64], dt_s[64], w_s[64];
  int b = blockIdx.x;
  int c = b / NHEADS, h = b % NHEADS;
  int tid = threadIdx.x, w = tid >> 6, l = tid & 63;

  {
    const short* gC = BCbf + (size_t)(c * 64) * 128 + 64;
    const short* gB = BCbf + (size_t)(c * 64) * 128;
    const short* gX = XTall + (size_t)(h * 64) * 2048 + c * 64;
    const short* gT = BTg + c * 64;
#pragma unroll
    for (int q = 0; q < 2; q++) {
      int row = w * 16 + q * 8 + (l >> 3);
      int ks = (l & 7) ^ (row & 7);
      int lofs = (w * 16 + q * 8) * 64;
      gll16(gC + (size_t)row * 128 + ks * 8, Cl + lofs);
      gll16(gB + (size_t)row * 128 + ks * 8, Bl + lofs);
      gll16(gX + (size_t)row * 2048 + ks * 8, XTl + lofs);
      gll16(gT + (size_t)row * 2048 + ks * 8, BTl + lofs);
    }
  }
  if (tid < 64) {
    la_s[tid] = laB[(c * CHUNK + tid) * NHEADS + h];
    dt_s[tid] = dts[(c * CHUNK + tid) * NHEADS + h];
  }
  __syncthreads();

  // G = C @ B^T (wave w owns rows w*16..w*16+15)
  f32x4 gacc[4] = {};
#pragma unroll
  for (int kt = 0; kt < 2; kt++) {
    int ar = w * 16 + (l & 15);
    int kk = kt * 32 + (l >> 4) * 8;
    s16x8 af = *(const s16x8*)&Cl[SWZ(ar, kk)];
#pragma unroll
    for (int nj = 0; nj < 4; nj++) {
      s16x8 bf_ = *(const s16x8*)&Bl[SWZ(nj * 16 + (l & 15), kk)];
      gacc[nj] = __builtin_amdgcn_mfma_f32_16x16x32_bf16(af, bf_, gacc[nj], 0, 0, 0);
    }
  }
  if (tid < 64) w_s[tid] = __expf(la_s[63] - la_s[tid]) * dt_s[tid];
  // M[t,s] = G * exp(la_t - la_s) * dt_s  (s<=t), bf16 into Ml
#pragma unroll
  for (int nj = 0; nj < 4; nj++)
#pragma unroll
    for (int r = 0; r < 4; r++) {
      int t = w * 16 + (l >> 4) * 4 + r;
      int s = nj * 16 + (l & 15);
      float m = (s <= t) ? gacc[nj][r] * __expf(la_s[t] - la_s[s]) * dt_s[s] : 0.f;
      Ml[SWZ(t, s)] = f2bf(m);
    }
  __syncthreads();
  // scale BTl[s][t] *= w[t]
  {
    int s = tid & 63, tg = (tid >> 6) * 16;
#pragma unroll
    for (int j = 0; j < 16; j++) {
      int t = tg + j;
      int a = SWZ(s, t);
      BTl[a] = f2bf(bf2f(BTl[a]) * w_s[t]);
    }
  }
  __syncthreads();

  // y_diag[t,p] = sum_s M[t,s] * XT[p,s]
  f32x4 yacc[4] = {};
#pragma unroll
  for (int kt = 0; kt < 2; kt++) {
    int ar = w * 16 + (l & 15);
    int kk = kt * 32 + (l >> 4) * 8;
    s16x8 af = *(const s16x8*)&Ml[SWZ(ar, kk)];
#pragma unroll
    for (int nj = 0; nj < 4; nj++) {
      s16x8 bf_ = *(const s16x8*)&XTl[SWZ(nj * 16 + (l & 15), kk)];
      yacc[nj] = __builtin_amdgcn_mfma_f32_16x16x32_bf16(af, bf_, yacc[nj], 0, 0, 0);
    }
  }
  // h_end[p,s] = sum_t XT[p,t]*w[t]*B[t,s]
  f32x4 hacc[4] = {};
#pragma unroll
  for (int kt = 0; kt < 2; kt++) {
    int ar = w * 16 + (l & 15);
    int kk = kt * 32 + (l >> 4) * 8;
    s16x8 af = *(const s16x8*)&XTl[SWZ(ar, kk)];
#pragma unroll
    for (int nj = 0; nj < 4; nj++) {
      s16x8 bf_ = *(const s16x8*)&BTl[SWZ(nj * 16 + (l & 15), kk)];
      hacc[nj] = __builtin_amdgcn_mfma_f32_16x16x32_bf16(af, bf_, hacc[nj], 0, 0, 0);
    }
  }
#pragma unroll
  for (int nj = 0; nj < 4; nj++)
#pragma unroll
    for (int r = 0; r < 4; r++) {
      int t = w * 16 + (l >> 4) * 4 + r;
      int p = nj * 16 + (l & 15);
      ylg[(size_t)(c * CHUNK + t) * D_INNER + h * 64 + p] = f2bf(yacc[nj][r]);
      // for h_end: role swap (t->p, p->s)
      Sb[((size_t)(c * NHEADS + h) * 64 + t) * 64 + p] = hacc[nj][r];
    }
}

// ---- scan pass 2: chunk combine; emits h_start in bf16 (Hsbf) ---------------
__global__ __launch_bounds__(256) void scan2_kernel(const float* __restrict__ Sb,
                                                    const float* __restrict__ laB,
                                                    short* __restrict__ Hsbf) {
  int idx = blockIdx.x * 256 + threadIdx.x;  // [0, 24*4096)
  int hh = idx >> 12;
  int rem = idx & 4095;  // p*64 + s
  float Sv[NCHUNK];
#pragma unroll
  for (int c = 0; c < NCHUNK; c++)
    Sv[c] = Sb[((size_t)c * NHEADS + hh) * 4096 + rem];
  float run = 0.f;
#pragma unroll
  for (int c = 0; c < NCHUNK; c++) {
    float P = __expf(laB[(c * CHUNK + CHUNK - 1) * NHEADS + hh]);
    Hsbf[((size_t)c * NHEADS + hh) * 4096 + rem] = f2bf(run);
    run = fmaf(P, run, Sv[c]);
  }
}

// ------- SSD-B per (chunk,head): y += exp(la_t)*C@h_start^T + D*xs; gate ----
__global__ __launch_bounds__(256) void ssd_b_kernel(const short* __restrict__ BCbf,
                                                    const short* __restrict__ Hsbf,
                                                    const float* __restrict__ laB,
                                                    const float* __restrict__ Dsk,
                                                    const float* __restrict__ xbc,
                                                    const float* __restrict__ zx,
                                                    short* __restrict__ ylg) {
  __shared__ short Cl[4096], Hl[4096];
  __shared__ float la_s[64];
  int b = blockIdx.x;
  int c = b / NHEADS, h = b % NHEADS;
  int tid = threadIdx.x, w = tid >> 6, l = tid & 63;
  {
    const short* gC = BCbf + (size_t)(c * 64) * 128 + 64;
    const short* gH = Hsbf + (size_t)(c * NHEADS + h) * 4096;
#pragma unroll
    for (int q = 0; q < 2; q++) {
      int row = w * 16 + q * 8 + (l >> 3);
      int ks = (l & 7) ^ (row & 7);
      int lofs = (w * 16 + q * 8) * 64;
      gll16(gC + (size_t)row * 128 + ks * 8, Cl + lofs);
      gll16(gH + (size_t)row * 64 + ks * 8, Hl + lofs);
    }
  }
  if (tid < 64) la_s[tid] = laB[(c * CHUNK + tid) * NHEADS + h];
  __syncthreads();
  f32x4 acc[4] = {};
#pragma unroll
  for (int kt = 0; kt < 2; kt++) {
    int ar = w * 16 + (l & 15);
    int kk = kt * 32 + (l >> 4) * 8;
    s16x8 af = *(const s16x8*)&Cl[SWZ(ar, kk)];
#pragma unroll
    for (int nj = 0; nj < 4; nj++) {
      s16x8 bf_ = *(const s16x8*)&Hl[SWZ(nj * 16 + (l & 15), kk)];
      acc[nj] = __builtin_amdgcn_mfma_f32_16x16x32_bf16(af, bf_, acc[nj], 0, 0, 0);
    }
  }
  float Dv = Dsk[h];
#pragma unroll
  for (int nj = 0; nj < 4; nj++)
#pragma unroll
    for (int r = 0; r < 4; r++) {
      int t = w * 16 + (l >> 4) * 4 + r;
      int p = nj * 16 + (l & 15);
      size_t gt = c * CHUNK + t;
      size_t gi = gt * D_INNER + h * 64 + p;
      float yv = bf2f(ylg[gi]) + acc[nj][r] * __expf(la_s[t]) +
                 Dv * xbc[gt * CONV_DIM + h * 64 + p];
      float z = zx[gt * D_IN_PROJ + h * 64 + p];
      ylg[gi] = f2bf(yv * silu_f(z));
    }
}

// ---------------- RMSNorm over D_INNER (bf16 in), writes bf16 ---------------
__global__ __launch_bounds__(256) void rmsnorm_bf_kernel(const short* __restrict__ g,
                                                         const float* __restrict__ nw,
                                                         short* __restrict__ ybn) {
  __shared__ float red[8];
  int t = blockIdx.x;
  const short* gr = g + (size_t)t * D_INNER;
  float v[6];
  float ss = 0.f;
#pragma unroll
  for (int k = 0; k < 6; k++) {
    v[k] = bf2f(gr[threadIdx.x + k * 256]);
    ss += v[k] * v[k];
  }
  ss = block_sum256(ss, red);
  float rs = rsqrtf(ss * (1.f / (float)D_INNER) + EPS);
  short* orow = ybn + (size_t)t * D_INNER;
#pragma unroll
  for (int k = 0; k < 6; k++) {
    int i = threadIdx.x + k * 256;
    orow[i] = f2bf(v[k] * rs * nw[i]);
  }
}

// ---------------- GLU: g = f[:, :H] * silu(f[:, H:2H]) -> bf16 --------------
__global__ void glu_kernel(const float* __restrict__ f, short* __restrict__ g) {
  int idx = blockIdx.x * 256 + threadIdx.x;
  if (idx >= SEQ * HIDDEN) return;
  int t = idx / HIDDEN, i = idx % HIDDEN;
  float a = f[(size_t)t * 2 * HIDDEN + i];
  float b = f[(size_t)t * 2 * HIDDEN + HIDDEN + i];
  g[idx] = f2bf(a * silu_f(b));
}

// ----------------------------------------------------------------------------
extern "C" void kernel_launch(void* const* d_in, const int* in_sizes, int n_in,
                              void* d_out, int out_size, void* d_ws, size_t ws_size,
                              hipStream_t stream) {
  const float* x     = (const float*)d_in[0];
  const float* ln1w  = (const float*)d_in[1];
  const float* ln1b  = (const float*)d_in[2];
  const float* ln2w  = (const float*)d_in[3];
  const float* ln2b  = (const float*)d_in[4];
  const float* Win   = (const float*)d_in[5];
  const float* convw = (const float*)d_in[6];
  const float* convb = (const float*)d_in[7];
  const float* dtb   = (const float*)d_in[8];
  const float* Alog  = (const float*)d_in[9];
  const float* Dsk   = (const float*)d_in[10];
  const float* nrmw  = (const float*)d_in[11];
  const float* Wout  = (const float*)d_in[12];
  const float* Wfc1  = (const float*)d_in[13];
  const float* Wfc2  = (const float*)d_in[14];
  float* out = (float*)d_out;
  float* ws  = (float*)d_ws;

  // ---- workspace layout (float-equipped offsets; total 76.5 MB) ----
  float* zx    = ws;                         // 6,602,752 f (reused: fc1 out f)
  float* xbc   = zx + 6602752;               // 3,407,872 f (reused: gbf)
  short* ylg   = (short*)(xbc + 3407872);    // 3,145,728 sh  (y_diag -> gated y)
  float* Sb    = (float*)(ylg + 3145728);    // 3,145,728 f (h_end; then x1+ybn)
  float* dts   = Sb + 3145728;               // 49,152 f
  float* laB   = dts + 49152;                // 49,152 f (log dA -> cumsum la)
  short* hbf   = (short*)(laB + 49152);      // 1,572,864 sh
  short* WA    = hbf + 1572864;              // 2,555,904 sh
  short* WB    = WA + 2555904;               // 1,179,648 sh
  short* XTall = WB + 1179648;               // 3,145,728 sh (xs^T; then Hsbf)
  short* BTg   = XTall + 3145728;            // 131,072 sh (B^T)

  short* BCbf = WB;                          // 262,144 sh overlay (dead < Wout cast)
  short* Hsbf = XTall;                       // overlay (XTall dead after ssd_a)
  float* x1   = Sb;                          // after scan2
  short* ybn  = (short*)(Sb + 1572864);
  float* f    = zx;
  short* gbf  = (short*)xbc;

  // 1) in_proj weight cast (pad 3224->3328 rows)
  castpad_kernel<<<(3328 * 768 + 255) / 256, 256, 0, stream>>>(Win, WA, 3328 * 768, 3224 * 768);
  // 2) LN1 -> bf16
  ln_kernel<<<SEQ, 256, 0, stream>>>(x, ln1w, ln1b, hbf);
  // 3) in_proj: zx = h @ Win^T
  mfma_gemm_bt<4><<<dim3(26, 16), 256, 0, stream>>>(hbf, WA, zx, nullptr, SEQ, D_IN_PROJ, D_MODEL);
  // 4) conv + silu
  conv_silu_kernel<<<(SEQ * CONV_DIM + 255) / 256, 256, 0, stream>>>(zx, convw, convb, xbc);
  // 5) dt / log dA, then chunk-local cumsum la
  dt_kernel<<<(SEQ * NHEADS + 255) / 256, 256, 0, stream>>>(zx, dtb, Alog, dts, laB);
  la_scan_kernel<<<192, 256, 0, stream>>>(laB);
  // 6) pack MFMA layouts
  postpack_kernel<<<dim3(26, 32), 256, 0, stream>>>(xbc, XTall, BTg, BCbf);
  // 7) SSD: diag blocks + chunk states, combine, off-diag correction + gate
  ssd_a_kernel<<<NCHUNK * NHEADS, 256, 0, stream>>>(BCbf, XTall, BTg, laB, dts, ylg, Sb);
  scan2_kernel<<<(NHEADS * 4096) / 256, 256, 0, stream>>>(Sb, laB, Hsbf);
  ssd_b_kernel<<<NCHUNK * NHEADS, 256, 0, stream>>>(BCbf, Hsbf, laB, Dsk, xbc, zx, ylg);
  // 8) RMSNorm -> bf16
  rmsnorm_bf_kernel<<<SEQ, 256, 0, stream>>>(ylg, nrmw, ybn);
  // 9) out_proj + residual
  castpad_kernel<<<(768 * 1536 + 255) / 256, 256, 0, stream>>>(Wout, WB, 768 * 1536, 768 * 1536);
  mfma_gemm_bt<2><<<dim3(6, 32), 256, 0, stream>>>(ybn, WB, x1, x, SEQ, D_MODEL, D_INNER);
  // 10) LN2 -> bf16
  ln_kernel<<<SEQ, 256, 0, stream>>>(x1, ln2w, ln2b, hbf);
  // 11) fc1
  castpad_kernel<<<(3072 * 768 + 255) / 256, 256, 0, stream>>>(Wfc1, WA, 3072 * 768, 3072 * 768);
  mfma_gemm_bt<4><<<dim3(24, 16), 256, 0, stream>>>(hbf, WA, f, nullptr, SEQ, 2 * HIDDEN, D_MODEL);
  // 12) GLU -> bf16
  glu_kernel<<<(SEQ * HIDDEN + 255) / 256, 256, 0, stream>>>(f, gbf);
  // 13) fc2 + residual
  castpad_kernel<<<(768 * 1536 + 255) / 256, 256, 0, stream>>>(Wfc2, WB, 768 * 1536, 768 * 1536);
  mfma_gemm_bt<2><<<dim3(6, 32), 256, 0, stream>>>(gbf, WB, out, x1, SEQ, D_MODEL, HIDDEN);
}

// Round 5
// 201.142 us; speedup vs baseline: 4.0280x; 1.0949x over previous
//
#include <hip/hip_runtime.h>
#include <math.h>

#define D_MODEL 768
#define SEQ 2048
#define D_STATE 64
#define D_CONV 4
#define D_INNER 1536
#define HEADDIM 64
#define NHEADS 24
#define CONV_DIM 1664      // D_INNER + 2*D_STATE
#define D_IN_PROJ 3224     // 2*D_INNER + 2*D_STATE + NHEADS
#define HIDDEN 1536
#define EPS 1e-5f
#define NCHUNK 32
#define CHUNK 64

typedef short s16x8 __attribute__((ext_vector_type(8)));
typedef float f32x4 __attribute__((ext_vector_type(4)));

// XOR-swizzled 64x64 bf16 tile accessor: row-stride 64 shorts, 8-short slots,
// slot ^= (row&7). Involution (self-inverse).
#define SWZ(row, k) (((row) << 6) + ((((k) >> 3) ^ ((row) & 7)) << 3) + ((k) & 7))

// ---------------- helpers ---------------------------------------------------
__device__ __forceinline__ float silu_f(float x) { return x / (1.f + expf(-x)); }

__device__ __forceinline__ short f2bf(float x) {  // RNE fp32 -> bf16 bits
  unsigned u = __builtin_bit_cast(unsigned, x);
  unsigned r = (u + 0x7fffu + ((u >> 16) & 1u)) >> 16;
  return (short)r;
}
__device__ __forceinline__ float bf2f(short s) {
  unsigned u = ((unsigned)(unsigned short)s) << 16;
  return __builtin_bit_cast(float, u);
}

__device__ __forceinline__ float block_sum256(float v, float* sdata) {
#pragma unroll
  for (int o = 32; o > 0; o >>= 1) v += __shfl_down(v, o);
  int lane = threadIdx.x & 63, wid = threadIdx.x >> 6;
  __syncthreads();
  if (lane == 0) sdata[wid] = v;
  __syncthreads();
  if (threadIdx.x == 0) sdata[0] = sdata[0] + sdata[1] + sdata[2] + sdata[3];
  __syncthreads();
  return sdata[0];
}

// async 16B global->LDS (dest: wave-uniform base + lane*16)
__device__ __forceinline__ void gll16(const short* gsrc, const short* ldst) {
  __builtin_amdgcn_global_load_lds(
      (const __attribute__((address_space(1))) unsigned int*)(unsigned long long)gsrc,
      (__attribute__((address_space(3))) unsigned int*)(unsigned int)(unsigned long long)ldst,
      16, 0, 0);
}

// ---------------- LayerNorm over 768, writes bf16 ---------------------------
__global__ __launch_bounds__(256) void ln_kernel(const float* __restrict__ x,
                                                 const float* __restrict__ w,
                                                 const float* __restrict__ b,
                                                 short* __restrict__ out) {
  __shared__ float red[8];
  int row = blockIdx.x;
  const float* xr = x + (size_t)row * D_MODEL;
  float v[3];
#pragma unroll
  for (int k = 0; k < 3; k++) v[k] = xr[threadIdx.x + k * 256];
  float s = v[0] + v[1] + v[2];
  s = block_sum256(s, red);
  float mean = s * (1.f / 768.f);
  float q = 0.f;
#pragma unroll
  for (int k = 0; k < 3; k++) { float d = v[k] - mean; q += d * d; }
  q = block_sum256(q, red);
  float rstd = rsqrtf(q * (1.f / 768.f) + EPS);
  short* orow = out + (size_t)row * D_MODEL;
#pragma unroll
  for (int k = 0; k < 3; k++) {
    int i = threadIdx.x + k * 256;
    orow[i] = f2bf((v[k] - mean) * rstd * w[i] + b[i]);
  }
}

// ---------------- weight cast fp32 -> bf16 with row padding -----------------
__global__ void castpad_kernel(const float* __restrict__ src, short* __restrict__ dst,
                               int total, int realtotal) {
  int idx = blockIdx.x * 256 + threadIdx.x;
  if (idx >= total) return;
  dst[idx] = (idx < realtotal) ? f2bf(src[idx]) : (short)0;
}

// ------- cast fc1 weight with row interleave: dst row 2j=src j, 2j+1=src H+j -
__global__ void cast_fc1i_kernel(const float* __restrict__ src, short* __restrict__ dst) {
  int idx = blockIdx.x * 256 + threadIdx.x;
  if (idx >= 3072 * 768) return;
  int np = idx / 768, k = idx % 768;
  int srow = (np & 1) ? (HIDDEN + (np >> 1)) : (np >> 1);
  dst[idx] = f2bf(src[(size_t)srow * 768 + k]);
}

// ---------------- bf16 MFMA GEMM: C = A(MxK) * W(NpadxK)^T ------------------
// OMODE: 0 = fp32 out (+optional res), 1 = bf16 out, 2 = bf16 GLU-pair out
template <int MREP, int OMODE>
__global__ __launch_bounds__(256) void mfma_gemm_bt(const short* __restrict__ A,
                                                    const short* __restrict__ Bw,
                                                    void* __restrict__ Cout,
                                                    const float* __restrict__ res,
                                                    int M, int Nreal, int K) {
  constexpr int BMr = MREP * 32;
  __shared__ short As[BMr * 32];
  __shared__ short Bs[128 * 32];
  int tid = threadIdx.x, w = tid >> 6, l = tid & 63;
  int m0 = blockIdx.y * BMr, n0 = blockIdx.x * 128;
  int wr = (w >> 1) * (MREP * 16), wc = (w & 1) * 64;
  f32x4 acc[MREP][4] = {};

  for (int kt = 0; kt < K; kt += 32) {
    __syncthreads();
#pragma unroll
    for (int q = 0; q < BMr / 64; q++) {
      int chunk = w * (BMr / 64) + q;
      int row = chunk * 16 + (l >> 2);
      int gs = (l & 3) ^ (row & 3);
      gll16(A + (size_t)(m0 + row) * K + kt + gs * 8, As + chunk * 512);
    }
#pragma unroll
    for (int q = 0; q < 2; q++) {
      int chunk = w * 2 + q;
      int row = chunk * 16 + (l >> 2);
      int gs = (l & 3) ^ (row & 3);
      gll16(Bw + (size_t)(n0 + row) * K + kt + gs * 8, Bs + chunk * 512);
    }
    __syncthreads();
    s16x8 af[MREP], bfr[4];
#pragma unroll
    for (int mi = 0; mi < MREP; mi++) {
      int row = wr + mi * 16 + (l & 15);
      int sl = (l >> 4) ^ (row & 3);
      af[mi] = *(const s16x8*)&As[row * 32 + sl * 8];
    }
#pragma unroll
    for (int nj = 0; nj < 4; nj++) {
      int row = wc + nj * 16 + (l & 15);
      int sl = (l >> 4) ^ (row & 3);
      bfr[nj] = *(const s16x8*)&Bs[row * 32 + sl * 8];
    }
#pragma unroll
    for (int mi = 0; mi < MREP; mi++)
#pragma unroll
      for (int nj = 0; nj < 4; nj++)
        acc[mi][nj] = __builtin_amdgcn_mfma_f32_16x16x32_bf16(af[mi], bfr[nj],
                                                              acc[mi][nj], 0, 0, 0);
  }
  // epilogue: C/D map col=lane&15, row=(lane>>4)*4+reg  [m89-verified]
#pragma unroll
  for (int mi = 0; mi < MREP; mi++)
#pragma unroll
    for (int nj = 0; nj < 4; nj++)
#pragma unroll
      for (int r = 0; r < 4; r++) {
        int mm = m0 + wr + mi * 16 + (l >> 4) * 4 + r;
        int nn = n0 + wc + nj * 16 + (l & 15);
        float v = acc[mi][nj][r];
        if constexpr (OMODE == 0) {
          float* C = (float*)Cout;
          if (nn < Nreal) {
            if (res) v += res[(size_t)mm * Nreal + nn];
            C[(size_t)mm * Nreal + nn] = v;
          }
        } else if constexpr (OMODE == 1) {
          short* C = (short*)Cout;
          if (nn < Nreal) C[(size_t)mm * Nreal + nn] = f2bf(v);
        } else {
          // GLU pair: even col = a, odd col = b (partner lane l^1); out = a*silu(b)
          float pv = __shfl_xor(v, 1);
          if ((l & 1) == 0) {
            short* g = (short*)Cout;
            g[(size_t)mm * (Nreal >> 1) + (nn >> 1)] = f2bf(v * silu_f(pv));
          }
        }
      }
}

// ------- fused causal conv4 + bias + SiLU + pack (XTall, BTg, BCbf, xs) -----
__global__ __launch_bounds__(256) void conv_pack_kernel(const short* __restrict__ zx,
                                                        const float* __restrict__ cw,
                                                        const float* __restrict__ cb,
                                                        short* __restrict__ xsb,
                                                        short* __restrict__ XTall,
                                                        short* __restrict__ BTg,
                                                        short* __restrict__ BCbf) {
  __shared__ float T[64][65];
  int ct = blockIdx.x, rt = blockIdx.y;
  int lane = threadIdx.x & 63, grp = threadIdx.x >> 6;
  int c = ct * 64 + lane;
  float4 w4 = *(const float4*)&cw[c * 4];
  float cbv = cb[c];
  int t0 = rt * 64 + grp * 16;
  float vbuf[19];
#pragma unroll
  for (int jj = 0; jj < 19; jj++) {
    int tt = t0 + jj - 3;
    vbuf[jj] = (tt >= 0) ? bf2f(zx[(size_t)tt * D_IN_PROJ + D_INNER + c]) : 0.f;
  }
#pragma unroll
  for (int j = 0; j < 16; j++) {
    float acc = cbv + vbuf[j] * w4.x + vbuf[j + 1] * w4.y +
                vbuf[j + 2] * w4.z + vbuf[j + 3] * w4.w;
    float v = silu_f(acc);
    int row = grp * 16 + j;
    T[row][lane] = v;
    if (ct < 24)
      xsb[(size_t)(rt * 64 + row) * D_INNER + c] = f2bf(v);
    else
      BCbf[(size_t)(rt * 64 + row) * 128 + (ct - 24) * 64 + lane] = f2bf(v);
  }
  __syncthreads();
  if (ct < 24) {
#pragma unroll
    for (int j = 0; j < 16; j++) {
      int cc = grp * 16 + j;
      XTall[(size_t)(ct * 64 + cc) * 2048 + rt * 64 + lane] = f2bf(T[lane][cc]);
    }
  } else if (ct == 24) {
#pragma unroll
    for (int j = 0; j < 16; j++) {
      int cc = grp * 16 + j;
      BTg[(size_t)cc * 2048 + rt * 64 + lane] = f2bf(T[lane][cc]);
    }
  }
}

// ------- fused dt=softplus + la=-exp(A_log)*dt + chunk-local cumsum ---------
__global__ __launch_bounds__(256) void dtla_kernel(const short* __restrict__ zx,
                                                   const float* __restrict__ dtb,
                                                   const float* __restrict__ Alog,
                                                   float* __restrict__ dts,
                                                   float* __restrict__ laB) {
  int W = blockIdx.x * 4 + (threadIdx.x >> 6);  // 0..767 = (chunk, head)
  int c = W / NHEADS, h = W % NHEADS;
  int t = threadIdx.x & 63;
  int gt = c * CHUNK + t;
  float xv = bf2f(zx[(size_t)gt * D_IN_PROJ + 2 * D_INNER + 2 * D_STATE + h]) + dtb[h];
  float sp = (xv > 20.f) ? xv : log1pf(expf(xv));
  float la = -expf(Alog[h]) * sp;
#pragma unroll
  for (int off = 1; off < 64; off <<= 1) {
    float u = __shfl_up(la, off);
    if (t >= off) la += u;
  }
  dts[gt * NHEADS + h] = sp;
  laB[gt * NHEADS + h] = la;
}

// ------- SSD-A per (chunk,head): G=C@B^T, M, y_diag=M@X, h_end=(wX)^T@B -----
__global__ __launch_bounds__(256) void ssd_a_kernel(const short* __restrict__ BCbf,
                                                    const short* __restrict__ XTall,
                                                    const short* __restrict__ BTg,
                                                    const float* __restrict__ laB,
                                                    const float* __restrict__ dts,
                                                    short* __restrict__ ylg,
                                                    float* __restrict__ Sb) {
  __shared__ short Cl[4096], Bl[4096], XTl[4096], BTl[4096], Ml[4096];
  __shared__ float la_s[64], dt_s[64], w_s[64];
  int b = blockIdx.x;
  int c = b / NHEADS, h = b % NHEADS;
  int tid = threadIdx.x, w = tid >> 6, l = tid & 63;

  {
    const short* gC = BCbf + (size_t)(c * 64) * 128 + 64;
    const short* gB = BCbf + (size_t)(c * 64) * 128;
    const short* gX = XTall + (size_t)(h * 64) * 2048 + c * 64;
    const short* gT = BTg + c * 64;
#pragma unroll
    for (int q = 0; q < 2; q++) {
      int row = w * 16 + q * 8 + (l >> 3);
      int ks = (l & 7) ^ (row & 7);
      int lofs = (w * 16 + q * 8) * 64;
      gll16(gC + (size_t)row * 128 + ks * 8, Cl + lofs);
      gll16(gB + (size_t)row * 128 + ks * 8, Bl + lofs);
      gll16(gX + (size_t)row * 2048 + ks * 8, XTl + lofs);
      gll16(gT + (size_t)row * 2048 + ks * 8, BTl + lofs);
    }
  }
  if (tid < 64) {
    la_s[tid] = laB[(c * CHUNK + tid) * NHEADS + h];
    dt_s[tid] = dts[(c * CHUNK + tid) * NHEADS + h];
  }
  __syncthreads();

  // G = C @ B^T
  f32x4 gacc[4] = {};
#pragma unroll
  for (int kt = 0; kt < 2; kt++) {
    int ar = w * 16 + (l & 15);
    int kk = kt * 32 + (l >> 4) * 8;
    s16x8 af = *(const s16x8*)&Cl[SWZ(ar, kk)];
#pragma unroll
    for (int nj = 0; nj < 4; nj++) {
      s16x8 bf_ = *(const s16x8*)&Bl[SWZ(nj * 16 + (l & 15), kk)];
      gacc[nj] = __builtin_amdgcn_mfma_f32_16x16x32_bf16(af, bf_, gacc[nj], 0, 0, 0);
    }
  }
  if (tid < 64) w_s[tid] = __expf(la_s[63] - la_s[tid]) * dt_s[tid];
  // M[t,s] = G * exp(la_t - la_s) * dt_s  (s<=t)
#pragma unroll
  for (int nj = 0; nj < 4; nj++)
#pragma unroll
    for (int r = 0; r < 4; r++) {
      int t = w * 16 + (l >> 4) * 4 + r;
      int s = nj * 16 + (l & 15);
      float m = (s <= t) ? gacc[nj][r] * __expf(la_s[t] - la_s[s]) * dt_s[s] : 0.f;
      Ml[SWZ(t, s)] = f2bf(m);
    }
  __syncthreads();
  // scale BTl[s][t] *= w[t]
  {
    int s = tid & 63, tg = (tid >> 6) * 16;
#pragma unroll
    for (int j = 0; j < 16; j++) {
      int t = tg + j;
      int a = SWZ(s, t);
      BTl[a] = f2bf(bf2f(BTl[a]) * w_s[t]);
    }
  }
  __syncthreads();

  // y_diag[t,p] = sum_s M[t,s] * XT[p,s]
  f32x4 yacc[4] = {};
#pragma unroll
  for (int kt = 0; kt < 2; kt++) {
    int ar = w * 16 + (l & 15);
    int kk = kt * 32 + (l >> 4) * 8;
    s16x8 af = *(const s16x8*)&Ml[SWZ(ar, kk)];
#pragma unroll
    for (int nj = 0; nj < 4; nj++) {
      s16x8 bf_ = *(const s16x8*)&XTl[SWZ(nj * 16 + (l & 15), kk)];
      yacc[nj] = __builtin_amdgcn_mfma_f32_16x16x32_bf16(af, bf_, yacc[nj], 0, 0, 0);
    }
  }
  // h_end[p,s] = sum_t XT[p,t]*w[t]*B[t,s]
  f32x4 hacc[4] = {};
#pragma unroll
  for (int kt = 0; kt < 2; kt++) {
    int ar = w * 16 + (l & 15);
    int kk = kt * 32 + (l >> 4) * 8;
    s16x8 af = *(const s16x8*)&XTl[SWZ(ar, kk)];
#pragma unroll
    for (int nj = 0; nj < 4; nj++) {
      s16x8 bf_ = *(const s16x8*)&BTl[SWZ(nj * 16 + (l & 15), kk)];
      hacc[nj] = __builtin_amdgcn_mfma_f32_16x16x32_bf16(af, bf_, hacc[nj], 0, 0, 0);
    }
  }
#pragma unroll
  for (int nj = 0; nj < 4; nj++)
#pragma unroll
    for (int r = 0; r < 4; r++) {
      int t = w * 16 + (l >> 4) * 4 + r;
      int p = nj * 16 + (l & 15);
      ylg[(size_t)(c * CHUNK + t) * D_INNER + h * 64 + p] = f2bf(yacc[nj][r]);
      Sb[((size_t)(c * NHEADS + h) * 64 + t) * 64 + p] = hacc[nj][r];
    }
}

// ---- scan pass 2: chunk combine; emits h_start in bf16 (Hsbf) ---------------
__global__ __launch_bounds__(256) void scan2_kernel(const float* __restrict__ Sb,
                                                    const float* __restrict__ laB,
                                                    short* __restrict__ Hsbf) {
  int idx = blockIdx.x * 256 + threadIdx.x;  // [0, 24*4096)
  int hh = idx >> 12;
  int rem = idx & 4095;  // p*64 + s
  float Sv[NCHUNK];
#pragma unroll
  for (int c = 0; c < NCHUNK; c++)
    Sv[c] = Sb[((size_t)c * NHEADS + hh) * 4096 + rem];
  float run = 0.f;
#pragma unroll
  for (int c = 0; c < NCHUNK; c++) {
    float P = __expf(laB[(c * CHUNK + CHUNK - 1) * NHEADS + hh]);
    Hsbf[((size_t)c * NHEADS + hh) * 4096 + rem] = f2bf(run);
    run = fmaf(P, run, Sv[c]);
  }
}

// ------- SSD-B per (chunk,head): y += exp(la_t)*C@h_start^T + D*xs; gate ----
__global__ __launch_bounds__(256) void ssd_b_kernel(const short* __restrict__ BCbf,
                                                    const short* __restrict__ Hsbf,
                                                    const float* __restrict__ laB,
                                                    const float* __restrict__ Dsk,
                                                    const short* __restrict__ xsb,
                                                    const short* __restrict__ zx,
                                                    short* __restrict__ ylg) {
  __shared__ short Cl[4096], Hl[4096];
  __shared__ float la_s[64];
  int b = blockIdx.x;
  int c = b / NHEADS, h = b % NHEADS;
  int tid = threadIdx.x, w = tid >> 6, l = tid & 63;
  {
    const short* gC = BCbf + (size_t)(c * 64) * 128 + 64;
    const short* gH = Hsbf + (size_t)(c * NHEADS + h) * 4096;
#pragma unroll
    for (int q = 0; q < 2; q++) {
      int row = w * 16 + q * 8 + (l >> 3);
      int ks = (l & 7) ^ (row & 7);
      int lofs = (w * 16 + q * 8) * 64;
      gll16(gC + (size_t)row * 128 + ks * 8, Cl + lofs);
      gll16(gH + (size_t)row * 64 + ks * 8, Hl + lofs);
    }
  }
  if (tid < 64) la_s[tid] = laB[(c * CHUNK + tid) * NHEADS + h];
  __syncthreads();
  f32x4 acc[4] = {};
#pragma unroll
  for (int kt = 0; kt < 2; kt++) {
    int ar = w * 16 + (l & 15);
    int kk = kt * 32 + (l >> 4) * 8;
    s16x8 af = *(const s16x8*)&Cl[SWZ(ar, kk)];
#pragma unroll
    for (int nj = 0; nj < 4; nj++) {
      s16x8 bf_ = *(const s16x8*)&Hl[SWZ(nj * 16 + (l & 15), kk)];
      acc[nj] = __builtin_amdgcn_mfma_f32_16x16x32_bf16(af, bf_, acc[nj], 0, 0, 0);
    }
  }
  float Dv = Dsk[h];
#pragma unroll
  for (int nj = 0; nj < 4; nj++)
#pragma unroll
    for (int r = 0; r < 4; r++) {
      int t = w * 16 + (l >> 4) * 4 + r;
      int p = nj * 16 + (l & 15);
      size_t gt = c * CHUNK + t;
      size_t gi = gt * D_INNER + h * 64 + p;
      float yv = bf2f(ylg[gi]) + acc[nj][r] * __expf(la_s[t]) +
                 Dv * bf2f(xsb[gt * D_INNER + h * 64 + p]);
      float z = bf2f(zx[gt * D_IN_PROJ + h * 64 + p]);
      ylg[gi] = f2bf(yv * silu_f(z));
    }
}

// ---------------- RMSNorm over D_INNER (bf16 in), writes bf16 ---------------
__global__ __launch_bounds__(256) void rmsnorm_bf_kernel(const short* __restrict__ g,
                                                         const float* __restrict__ nw,
                                                         short* __restrict__ ybn) {
  __shared__ float red[8];
  int t = blockIdx.x;
  const short* gr = g + (size_t)t * D_INNER;
  float v[6];
  float ss = 0.f;
#pragma unroll
  for (int k = 0; k < 6; k++) {
    v[k] = bf2f(gr[threadIdx.x + k * 256]);
    ss += v[k] * v[k];
  }
  ss = block_sum256(ss, red);
  float rs = rsqrtf(ss * (1.f / (float)D_INNER) + EPS);
  short* orow = ybn + (size_t)t * D_INNER;
#pragma unroll
  for (int k = 0; k < 6; k++) {
    int i = threadIdx.x + k * 256;
    orow[i] = f2bf(v[k] * rs * nw[i]);
  }
}

// ----------------------------------------------------------------------------
extern "C" void kernel_launch(void* const* d_in, const int* in_sizes, int n_in,
                              void* d_out, int out_size, void* d_ws, size_t ws_size,
                              hipStream_t stream) {
  const float* x     = (const float*)d_in[0];
  const float* ln1w  = (const float*)d_in[1];
  const float* ln1b  = (const float*)d_in[2];
  const float* ln2w  = (const float*)d_in[3];
  const float* ln2b  = (const float*)d_in[4];
  const float* Win   = (const float*)d_in[5];
  const float* convw = (const float*)d_in[6];
  const float* convb = (const float*)d_in[7];
  const float* dtb   = (const float*)d_in[8];
  const float* Alog  = (const float*)d_in[9];
  const float* Dsk   = (const float*)d_in[10];
  const float* nrmw  = (const float*)d_in[11];
  const float* Wout  = (const float*)d_in[12];
  const float* Wfc1  = (const float*)d_in[13];
  const float* Wfc2  = (const float*)d_in[14];
  float* out = (float*)d_out;

  // ---- workspace layout (total ~56 MB) ----
  short* zxb   = (short*)d_ws;               // 6,602,752 sh (bf16 zx; reused: gbf)
  short* xsb   = zxb + 6602752;              // 3,145,728 sh (bf16 xs)
  short* ylg   = xsb + 3145728;              // 3,145,728 sh (y_diag -> gated y)
  float* Sb    = (float*)(ylg + 3145728);    // 3,145,728 f (h_end; then x1+ybn)
  float* dts   = Sb + 3145728;               // 49,152 f
  float* laB   = dts + 49152;                // 49,152 f
  short* hbf   = (short*)(laB + 49152);      // 1,572,864 sh
  short* WA    = hbf + 1572864;              // 2,555,904 sh (Win pad / fc1 interleave)
  short* WB    = WA + 2555904;               // 1,179,648 sh (Wout / Wfc2)
  short* XTall = WB + 1179648;               // 3,145,728 sh (xs^T; then Hsbf)
  short* BTg   = XTall + 3145728;            // 131,072 sh (B^T)

  short* BCbf = WB;                          // overlay: dead before Wout cast
  short* Hsbf = XTall;                       // overlay: XTall dead after ssd_a
  float* x1   = Sb;                          // overlay: Sb dead after scan2
  short* ybn  = (short*)(Sb + 1572864);
  short* gbf  = zxb;                         // overlay: zx dead after ssd_b

  // 1) in_proj weight cast (pad 3224->3328 rows)
  castpad_kernel<<<(3328 * 768 + 255) / 256, 256, 0, stream>>>(Win, WA, 3328 * 768, 3224 * 768);
  // 2) LN1 -> bf16
  ln_kernel<<<SEQ, 256, 0, stream>>>(x, ln1w, ln1b, hbf);
  // 3) in_proj: zx = h @ Win^T  -> bf16
  mfma_gemm_bt<4, 1><<<dim3(26, 16), 256, 0, stream>>>(hbf, WA, zxb, nullptr, SEQ, D_IN_PROJ, D_MODEL);
  // 4) fused conv+silu+pack
  conv_pack_kernel<<<dim3(26, 32), 256, 0, stream>>>(zxb, convw, convb, xsb, XTall, BTg, BCbf);
  // 5) fused dt/softplus + log dA cumsum
  dtla_kernel<<<192, 256, 0, stream>>>(zxb, dtb, Alog, dts, laB);
  // 6) SSD: diag + chunk states, combine, off-diag + gate
  ssd_a_kernel<<<NCHUNK * NHEADS, 256, 0, stream>>>(BCbf, XTall, BTg, laB, dts, ylg, Sb);
  scan2_kernel<<<(NHEADS * 4096) / 256, 256, 0, stream>>>(Sb, laB, Hsbf);
  ssd_b_kernel<<<NCHUNK * NHEADS, 256, 0, stream>>>(BCbf, Hsbf, laB, Dsk, xsb, zxb, ylg);
  // 7) RMSNorm -> bf16
  rmsnorm_bf_kernel<<<SEQ, 256, 0, stream>>>(ylg, nrmw, ybn);
  // 8) out_proj + residual: x1 = x + y @ Wout^T
  castpad_kernel<<<(768 * 1536 + 255) / 256, 256, 0, stream>>>(Wout, WB, 768 * 1536, 768 * 1536);
  mfma_gemm_bt<2, 0><<<dim3(6, 32), 256, 0, stream>>>(ybn, WB, x1, x, SEQ, D_MODEL, D_INNER);
  // 9) LN2 -> bf16
  ln_kernel<<<SEQ, 256, 0, stream>>>(x1, ln2w, ln2b, hbf);
  // 10) fc1 with interleaved weight + fused GLU -> gbf bf16
  cast_fc1i_kernel<<<(3072 * 768 + 255) / 256, 256, 0, stream>>>(Wfc1, WA);
  mfma_gemm_bt<4, 2><<<dim3(24, 16), 256, 0, stream>>>(hbf, WA, gbf, nullptr, SEQ, 2 * HIDDEN, D_MODEL);
  // 11) fc2 + residual: out = x1 + g @ Wfc2^T
  castpad_kernel<<<(768 * 1536 + 255) / 256, 256, 0, stream>>>(Wfc2, WB, 768 * 1536, 768 * 1536);
  mfma_gemm_bt<2, 0><<<dim3(6, 32), 256, 0, stream>>>(gbf, WB, out, x1, SEQ, D_MODEL, HIDDEN);
}

// Round 6
// 179.732 us; speedup vs baseline: 4.5078x; 1.1191x over previous
//
#include <hip/hip_runtime.h>
#include <math.h>

#define D_MODEL 768
#define SEQ 2048
#define D_STATE 64
#define D_CONV 4
#define D_INNER 1536
#define HEADDIM 64
#define NHEADS 24
#define CONV_DIM 1664      // D_INNER + 2*D_STATE
#define D_IN_PROJ 3224     // 2*D_INNER + 2*D_STATE + NHEADS
#define HIDDEN 1536
#define EPS 1e-5f
#define NCHUNK 32
#define CHUNK 64

typedef short s16x8 __attribute__((ext_vector_type(8)));
typedef float f32x4 __attribute__((ext_vector_type(4)));

// XOR-swizzled 64x64 bf16 tile accessor (row-stride 64 shorts, 8-short slots)
#define SWZ(row, k) (((row) << 6) + ((((k) >> 3) ^ ((row) & 7)) << 3) + ((k) & 7))

// ---------------- helpers ---------------------------------------------------
__device__ __forceinline__ float silu_f(float x) { return x / (1.f + expf(-x)); }

__device__ __forceinline__ short f2bf(float x) {  // RNE fp32 -> bf16 bits
  unsigned u = __builtin_bit_cast(unsigned, x);
  unsigned r = (u + 0x7fffu + ((u >> 16) & 1u)) >> 16;
  return (short)r;
}
__device__ __forceinline__ float bf2f(short s) {
  unsigned u = ((unsigned)(unsigned short)s) << 16;
  return __builtin_bit_cast(float, u);
}

__device__ __forceinline__ float block_sum256(float v, float* sdata) {
#pragma unroll
  for (int o = 32; o > 0; o >>= 1) v += __shfl_down(v, o);
  int lane = threadIdx.x & 63, wid = threadIdx.x >> 6;
  __syncthreads();
  if (lane == 0) sdata[wid] = v;
  __syncthreads();
  if (threadIdx.x == 0) sdata[0] = sdata[0] + sdata[1] + sdata[2] + sdata[3];
  __syncthreads();
  return sdata[0];
}

// async 16B global->LDS (dest: wave-uniform base + lane*16)
__device__ __forceinline__ void gll16(const short* gsrc, const short* ldst) {
  __builtin_amdgcn_global_load_lds(
      (const __attribute__((address_space(1))) unsigned int*)(unsigned long long)gsrc,
      (__attribute__((address_space(3))) unsigned int*)(unsigned int)(unsigned long long)ldst,
      16, 0, 0);
}

// ---------------- LayerNorm over 768, writes bf16 ---------------------------
__global__ __launch_bounds__(256) void ln_kernel(const float* __restrict__ x,
                                                 const float* __restrict__ w,
                                                 const float* __restrict__ b,
                                                 short* __restrict__ out) {
  __shared__ float red[8];
  int row = blockIdx.x;
  const float* xr = x + (size_t)row * D_MODEL;
  float v[3];
#pragma unroll
  for (int k = 0; k < 3; k++) v[k] = xr[threadIdx.x + k * 256];
  float s = v[0] + v[1] + v[2];
  s = block_sum256(s, red);
  float mean = s * (1.f / 768.f);
  float q = 0.f;
#pragma unroll
  for (int k = 0; k < 3; k++) { float d = v[k] - mean; q += d * d; }
  q = block_sum256(q, red);
  float rstd = rsqrtf(q * (1.f / 768.f) + EPS);
  short* orow = out + (size_t)row * D_MODEL;
#pragma unroll
  for (int k = 0; k < 3; k++) {
    int i = threadIdx.x + k * 256;
    orow[i] = f2bf((v[k] - mean) * rstd * w[i] + b[i]);
  }
}

// ------- fused weight cast: WinP | fc1-interleave | Wout | Wfc2 -------------
#define T_WINP (3328 * 768)
#define R_WINP (3224 * 768)
#define T_FC1 (3072 * 768)
#define T_W768 (1536 * 768)
__global__ void cast_weights_kernel(const float* __restrict__ Win,
                                    const float* __restrict__ Wfc1,
                                    const float* __restrict__ Wout,
                                    const float* __restrict__ Wfc2,
                                    short* __restrict__ WA, short* __restrict__ WF1,
                                    short* __restrict__ WB, short* __restrict__ WC) {
  int idx = blockIdx.x * 256 + threadIdx.x;
  if (idx < T_WINP) {
    WA[idx] = (idx < R_WINP) ? f2bf(Win[idx]) : (short)0;
    return;
  }
  idx -= T_WINP;
  if (idx < T_FC1) {  // interleave: dst row 2j=src j, 2j+1=src H+j
    int np = idx / 768, k = idx % 768;
    int srow = (np & 1) ? (HIDDEN + (np >> 1)) : (np >> 1);
    WF1[idx] = f2bf(Wfc1[(size_t)srow * 768 + k]);
    return;
  }
  idx -= T_FC1;
  if (idx < T_W768) { WB[idx] = f2bf(Wout[idx]); return; }
  idx -= T_W768;
  if (idx < T_W768) WC[idx] = f2bf(Wfc2[idx]);
}

// ---------------- bf16 MFMA GEMM: C = A(MxK) * W(NpadxK)^T ------------------
// tile = (MREP*32) x (NREP*32); 256 threads = 4 waves (2x2).
// OMODE: 0 = fp32 out (+optional res), 1 = bf16 out, 2 = bf16 GLU-pair out
template <int MREP, int NREP, int OMODE>
__global__ __launch_bounds__(256) void mfma_gemm_bt(const short* __restrict__ A,
                                                    const short* __restrict__ Bw,
                                                    void* __restrict__ Cout,
                                                    const float* __restrict__ res,
                                                    int M, int Nreal, int K) {
  constexpr int BMr = MREP * 32;
  constexpr int BNr = NREP * 32;
  __shared__ short As[BMr * 32];
  __shared__ short Bs[BNr * 32];
  int tid = threadIdx.x, w = tid >> 6, l = tid & 63;
  int m0 = blockIdx.y * BMr, n0 = blockIdx.x * BNr;
  int wr = (w >> 1) * (MREP * 16), wc = (w & 1) * (NREP * 16);
  f32x4 acc[MREP][NREP] = {};

  for (int kt = 0; kt < K; kt += 32) {
    __syncthreads();
#pragma unroll
    for (int q = 0; q < BMr / 64; q++) {
      int chunk = w * (BMr / 64) + q;
      int row = chunk * 16 + (l >> 2);
      int gs = (l & 3) ^ (row & 3);
      gll16(A + (size_t)(m0 + row) * K + kt + gs * 8, As + chunk * 512);
    }
#pragma unroll
    for (int q = 0; q < BNr / 64; q++) {
      int chunk = w * (BNr / 64) + q;
      int row = chunk * 16 + (l >> 2);
      int gs = (l & 3) ^ (row & 3);
      gll16(Bw + (size_t)(n0 + row) * K + kt + gs * 8, Bs + chunk * 512);
    }
    __syncthreads();
    s16x8 af[MREP], bfr[NREP];
#pragma unroll
    for (int mi = 0; mi < MREP; mi++) {
      int row = wr + mi * 16 + (l & 15);
      int sl = (l >> 4) ^ (row & 3);
      af[mi] = *(const s16x8*)&As[row * 32 + sl * 8];
    }
#pragma unroll
    for (int nj = 0; nj < NREP; nj++) {
      int row = wc + nj * 16 + (l & 15);
      int sl = (l >> 4) ^ (row & 3);
      bfr[nj] = *(const s16x8*)&Bs[row * 32 + sl * 8];
    }
#pragma unroll
    for (int mi = 0; mi < MREP; mi++)
#pragma unroll
      for (int nj = 0; nj < NREP; nj++)
        acc[mi][nj] = __builtin_amdgcn_mfma_f32_16x16x32_bf16(af[mi], bfr[nj],
                                                              acc[mi][nj], 0, 0, 0);
  }
  // epilogue: C/D map col=lane&15, row=(lane>>4)*4+reg  [m89-verified]
#pragma unroll
  for (int mi = 0; mi < MREP; mi++)
#pragma unroll
    for (int nj = 0; nj < NREP; nj++)
#pragma unroll
      for (int r = 0; r < 4; r++) {
        int mm = m0 + wr + mi * 16 + (l >> 4) * 4 + r;
        int nn = n0 + wc + nj * 16 + (l & 15);
        float v = acc[mi][nj][r];
        if constexpr (OMODE == 0) {
          float* C = (float*)Cout;
          if (nn < Nreal) {
            if (res) v += res[(size_t)mm * Nreal + nn];
            C[(size_t)mm * Nreal + nn] = v;
          }
        } else if constexpr (OMODE == 1) {
          short* C = (short*)Cout;
          if (nn < Nreal) C[(size_t)mm * Nreal + nn] = f2bf(v);
        } else {
          // GLU pair: even col = a, odd col = b (partner lane l^1); out = a*silu(b)
          float pv = __shfl_xor(v, 1);
          if ((l & 1) == 0) {
            short* g = (short*)Cout;
            g[(size_t)mm * (Nreal >> 1) + (nn >> 1)] = f2bf(v * silu_f(pv));
          }
        }
      }
}

// ------- fused conv4+SiLU+pack (ct<26) and dt/softplus/la-cumsum (ct==26) ---
__global__ __launch_bounds__(256) void conv_pack_kernel(const short* __restrict__ zx,
                                                        const float* __restrict__ cw,
                                                        const float* __restrict__ cb,
                                                        const float* __restrict__ dtb,
                                                        const float* __restrict__ Alog,
                                                        short* __restrict__ xsb,
                                                        short* __restrict__ XTall,
                                                        short* __restrict__ BTg,
                                                        short* __restrict__ BCbf,
                                                        float* __restrict__ dts,
                                                        float* __restrict__ laB) {
  int ct = blockIdx.x, rt = blockIdx.y;
  if (ct == 26) {  // dt path: chunk rt, 4 waves x 6 heads
    int wv = threadIdx.x >> 6, t = threadIdx.x & 63;
    int gt = rt * 64 + t;
#pragma unroll
    for (int i = 0; i < 6; i++) {
      int h = wv * 6 + i;
      float xv = bf2f(zx[(size_t)gt * D_IN_PROJ + 3200 + h]) + dtb[h];
      float sp = (xv > 20.f) ? xv : log1pf(expf(xv));
      float la = -expf(Alog[h]) * sp;
#pragma unroll
      for (int off = 1; off < 64; off <<= 1) {
        float u = __shfl_up(la, off);
        if (t >= off) la += u;
      }
      dts[gt * NHEADS + h] = sp;
      laB[gt * NHEADS + h] = la;
    }
    return;
  }
  __shared__ float T[64][65];
  int lane = threadIdx.x & 63, grp = threadIdx.x >> 6;
  int c = ct * 64 + lane;
  float4 w4 = *(const float4*)&cw[c * 4];
  float cbv = cb[c];
  int t0 = rt * 64 + grp * 16;
  float vbuf[19];
#pragma unroll
  for (int jj = 0; jj < 19; jj++) {
    int tt = t0 + jj - 3;
    vbuf[jj] = (tt >= 0) ? bf2f(zx[(size_t)tt * D_IN_PROJ + D_INNER + c]) : 0.f;
  }
#pragma unroll
  for (int j = 0; j < 16; j++) {
    float acc = cbv + vbuf[j] * w4.x + vbuf[j + 1] * w4.y +
                vbuf[j + 2] * w4.z + vbuf[j + 3] * w4.w;
    float v = silu_f(acc);
    int row = grp * 16 + j;
    T[row][lane] = v;
    if (ct < 24)
      xsb[(size_t)(rt * 64 + row) * D_INNER + c] = f2bf(v);
    else
      BCbf[(size_t)(rt * 64 + row) * 128 + (ct - 24) * 64 + lane] = f2bf(v);
  }
  __syncthreads();
  if (ct < 24) {
#pragma unroll
    for (int j = 0; j < 16; j++) {
      int cc = grp * 16 + j;
      XTall[(size_t)(ct * 64 + cc) * 2048 + rt * 64 + lane] = f2bf(T[lane][cc]);
    }
  } else if (ct == 24) {
#pragma unroll
    for (int j = 0; j < 16; j++) {
      int cc = grp * 16 + j;
      BTg[(size_t)cc * 2048 + rt * 64 + lane] = f2bf(T[lane][cc]);
    }
  }
}

// ------- SSD-A per (chunk,head): G=C@B^T, M, y_diag=M@X, h_end=(wX)^T@B -----
__global__ __launch_bounds__(256) void ssd_a_kernel(const short* __restrict__ BCbf,
                                                    const short* __restrict__ XTall,
                                                    const short* __restrict__ BTg,
                                                    const float* __restrict__ laB,
                                                    const float* __restrict__ dts,
                                                    short* __restrict__ ylg,
                                                    float* __restrict__ Sb) {
  __shared__ short Cl[4096], Bl[4096], XTl[4096], BTl[4096], Ml[4096];
  __shared__ float la_s[64], dt_s[64], w_s[64];
  int b = blockIdx.x;
  int c = b / NHEADS, h = b % NHEADS;
  int tid = threadIdx.x, w = tid >> 6, l = tid & 63;

  {
    const short* gC = BCbf + (size_t)(c * 64) * 128 + 64;
    const short* gB = BCbf + (size_t)(c * 64) * 128;
    const short* gX = XTall + (size_t)(h * 64) * 2048 + c * 64;
    const short* gT = BTg + c * 64;
#pragma unroll
    for (int q = 0; q < 2; q++) {
      int row = w * 16 + q * 8 + (l >> 3);
      int ks = (l & 7) ^ (row & 7);
      int lofs = (w * 16 + q * 8) * 64;
      gll16(gC + (size_t)row * 128 + ks * 8, Cl + lofs);
      gll16(gB + (size_t)row * 128 + ks * 8, Bl + lofs);
      gll16(gX + (size_t)row * 2048 + ks * 8, XTl + lofs);
      gll16(gT + (size_t)row * 2048 + ks * 8, BTl + lofs);
    }
  }
  if (tid < 64) {
    la_s[tid] = laB[(c * CHUNK + tid) * NHEADS + h];
    dt_s[tid] = dts[(c * CHUNK + tid) * NHEADS + h];
  }
  __syncthreads();

  // G = C @ B^T
  f32x4 gacc[4] = {};
#pragma unroll
  for (int kt = 0; kt < 2; kt++) {
    int ar = w * 16 + (l & 15);
    int kk = kt * 32 + (l >> 4) * 8;
    s16x8 af = *(const s16x8*)&Cl[SWZ(ar, kk)];
#pragma unroll
    for (int nj = 0; nj < 4; nj++) {
      s16x8 bf_ = *(const s16x8*)&Bl[SWZ(nj * 16 + (l & 15), kk)];
      gacc[nj] = __builtin_amdgcn_mfma_f32_16x16x32_bf16(af, bf_, gacc[nj], 0, 0, 0);
    }
  }
  if (tid < 64) w_s[tid] = __expf(la_s[63] - la_s[tid]) * dt_s[tid];
  // M[t,s] = G * exp(la_t - la_s) * dt_s  (s<=t)
#pragma unroll
  for (int nj = 0; nj < 4; nj++)
#pragma unroll
    for (int r = 0; r < 4; r++) {
      int t = w * 16 + (l >> 4) * 4 + r;
      int s = nj * 16 + (l & 15);
      float m = (s <= t) ? gacc[nj][r] * __expf(la_s[t] - la_s[s]) * dt_s[s] : 0.f;
      Ml[SWZ(t, s)] = f2bf(m);
    }
  __syncthreads();
  // scale BTl[s][t] *= w[t]
  {
    int s = tid & 63, tg = (tid >> 6) * 16;
#pragma unroll
    for (int j = 0; j < 16; j++) {
      int t = tg + j;
      int a = SWZ(s, t);
      BTl[a] = f2bf(bf2f(BTl[a]) * w_s[t]);
    }
  }
  __syncthreads();

  // y_diag[t,p] = sum_s M[t,s] * XT[p,s]
  f32x4 yacc[4] = {};
#pragma unroll
  for (int kt = 0; kt < 2; kt++) {
    int ar = w * 16 + (l & 15);
    int kk = kt * 32 + (l >> 4) * 8;
    s16x8 af = *(const s16x8*)&Ml[SWZ(ar, kk)];
#pragma unroll
    for (int nj = 0; nj < 4; nj++) {
      s16x8 bf_ = *(const s16x8*)&XTl[SWZ(nj * 16 + (l & 15), kk)];
      yacc[nj] = __builtin_amdgcn_mfma_f32_16x16x32_bf16(af, bf_, yacc[nj], 0, 0, 0);
    }
  }
  // h_end[p,s] = sum_t XT[p,t]*w[t]*B[t,s]
  f32x4 hacc[4] = {};
#pragma unroll
  for (int kt = 0; kt < 2; kt++) {
    int ar = w * 16 + (l & 15);
    int kk = kt * 32 + (l >> 4) * 8;
    s16x8 af = *(const s16x8*)&XTl[SWZ(ar, kk)];
#pragma unroll
    for (int nj = 0; nj < 4; nj++) {
      s16x8 bf_ = *(const s16x8*)&BTl[SWZ(nj * 16 + (l & 15), kk)];
      hacc[nj] = __builtin_amdgcn_mfma_f32_16x16x32_bf16(af, bf_, hacc[nj], 0, 0, 0);
    }
  }
#pragma unroll
  for (int nj = 0; nj < 4; nj++)
#pragma unroll
    for (int r = 0; r < 4; r++) {
      int t = w * 16 + (l >> 4) * 4 + r;
      int p = nj * 16 + (l & 15);
      ylg[(size_t)(c * CHUNK + t) * D_INNER + h * 64 + p] = f2bf(yacc[nj][r]);
      Sb[((size_t)(c * NHEADS + h) * 64 + t) * 64 + p] = hacc[nj][r];
    }
}

// ---- scan pass 2: chunk combine; emits h_start in bf16 (Hsbf) ---------------
__global__ __launch_bounds__(256) void scan2_kernel(const float* __restrict__ Sb,
                                                    const float* __restrict__ laB,
                                                    short* __restrict__ Hsbf) {
  int idx = blockIdx.x * 256 + threadIdx.x;  // [0, 24*4096)
  int hh = idx >> 12;
  int rem = idx & 4095;  // p*64 + s
  float Sv[NCHUNK];
#pragma unroll
  for (int c = 0; c < NCHUNK; c++)
    Sv[c] = Sb[((size_t)c * NHEADS + hh) * 4096 + rem];
  float run = 0.f;
#pragma unroll
  for (int c = 0; c < NCHUNK; c++) {
    float P = __expf(laB[(c * CHUNK + CHUNK - 1) * NHEADS + hh]);
    Hsbf[((size_t)c * NHEADS + hh) * 4096 + rem] = f2bf(run);
    run = fmaf(P, run, Sv[c]);
  }
}

// ------- SSD-B per (chunk,head): y += exp(la_t)*C@h_start^T + D*xs; gate ----
__global__ __launch_bounds__(256) void ssd_b_kernel(const short* __restrict__ BCbf,
                                                    const short* __restrict__ Hsbf,
                                                    const float* __restrict__ laB,
                                                    const float* __restrict__ Dsk,
                                                    const short* __restrict__ xsb,
                                                    const short* __restrict__ zx,
                                                    short* __restrict__ ylg) {
  __shared__ short Cl[4096], Hl[4096];
  __shared__ float la_s[64];
  int b = blockIdx.x;
  int c = b / NHEADS, h = b % NHEADS;
  int tid = threadIdx.x, w = tid >> 6, l = tid & 63;
  {
    const short* gC = BCbf + (size_t)(c * 64) * 128 + 64;
    const short* gH = Hsbf + (size_t)(c * NHEADS + h) * 4096;
#pragma unroll
    for (int q = 0; q < 2; q++) {
      int row = w * 16 + q * 8 + (l >> 3);
      int ks = (l & 7) ^ (row & 7);
      int lofs = (w * 16 + q * 8) * 64;
      gll16(gC + (size_t)row * 128 + ks * 8, Cl + lofs);
      gll16(gH + (size_t)row * 64 + ks * 8, Hl + lofs);
    }
  }
  if (tid < 64) la_s[tid] = laB[(c * CHUNK + tid) * NHEADS + h];
  __syncthreads();
  f32x4 acc[4] = {};
#pragma unroll
  for (int kt = 0; kt < 2; kt++) {
    int ar = w * 16 + (l & 15);
    int kk = kt * 32 + (l >> 4) * 8;
    s16x8 af = *(const s16x8*)&Cl[SWZ(ar, kk)];
#pragma unroll
    for (int nj = 0; nj < 4; nj++) {
      s16x8 bf_ = *(const s16x8*)&Hl[SWZ(nj * 16 + (l & 15), kk)];
      acc[nj] = __builtin_amdgcn_mfma_f32_16x16x32_bf16(af, bf_, acc[nj], 0, 0, 0);
    }
  }
  float Dv = Dsk[h];
#pragma unroll
  for (int nj = 0; nj < 4; nj++)
#pragma unroll
    for (int r = 0; r < 4; r++) {
      int t = w * 16 + (l >> 4) * 4 + r;
      int p = nj * 16 + (l & 15);
      size_t gt = c * CHUNK + t;
      size_t gi = gt * D_INNER + h * 64 + p;
      float yv = bf2f(ylg[gi]) + acc[nj][r] * __expf(la_s[t]) +
                 Dv * bf2f(xsb[gt * D_INNER + h * 64 + p]);
      float z = bf2f(zx[gt * D_IN_PROJ + h * 64 + p]);
      ylg[gi] = f2bf(yv * silu_f(z));
    }
}

// ---------------- RMSNorm over D_INNER (bf16 in), writes bf16 ---------------
__global__ __launch_bounds__(256) void rmsnorm_bf_kernel(const short* __restrict__ g,
                                                         const float* __restrict__ nw,
                                                         short* __restrict__ ybn) {
  __shared__ float red[8];
  int t = blockIdx.x;
  const short* gr = g + (size_t)t * D_INNER;
  float v[6];
  float ss = 0.f;
#pragma unroll
  for (int k = 0; k < 6; k++) {
    v[k] = bf2f(gr[threadIdx.x + k * 256]);
    ss += v[k] * v[k];
  }
  ss = block_sum256(ss, red);
  float rs = rsqrtf(ss * (1.f / (float)D_INNER) + EPS);
  short* orow = ybn + (size_t)t * D_INNER;
#pragma unroll
  for (int k = 0; k < 6; k++) {
    int i = threadIdx.x + k * 256;
    orow[i] = f2bf(v[k] * rs * nw[i]);
  }
}

// ----------------------------------------------------------------------------
extern "C" void kernel_launch(void* const* d_in, const int* in_sizes, int n_in,
                              void* d_out, int out_size, void* d_ws, size_t ws_size,
                              hipStream_t stream) {
  const float* x     = (const float*)d_in[0];
  const float* ln1w  = (const float*)d_in[1];
  const float* ln1b  = (const float*)d_in[2];
  const float* ln2w  = (const float*)d_in[3];
  const float* ln2b  = (const float*)d_in[4];
  const float* Win   = (const float*)d_in[5];
  const float* convw = (const float*)d_in[6];
  const float* convb = (const float*)d_in[7];
  const float* dtb   = (const float*)d_in[8];
  const float* Alog  = (const float*)d_in[9];
  const float* Dsk   = (const float*)d_in[10];
  const float* nrmw  = (const float*)d_in[11];
  const float* Wout  = (const float*)d_in[12];
  const float* Wfc1  = (const float*)d_in[13];
  const float* Wfc2  = (const float*)d_in[14];
  float* out = (float*)d_out;

  // ---- workspace layout (~64 MB) ----
  short* zxb   = (short*)d_ws;               // 6,602,752 sh (bf16 zx; reused: gbf)
  short* xsb   = zxb + 6602752;              // 3,145,728 sh
  short* ylg   = xsb + 3145728;              // 3,145,728 sh
  float* Sb    = (float*)(ylg + 3145728);    // 3,145,728 f (h_end; then x1+ybn)
  float* dts   = Sb + 3145728;               // 49,152 f
  float* laB   = dts + 49152;                // 49,152 f
  short* hbf   = (short*)(laB + 49152);      // 1,572,864 sh
  short* WA    = hbf + 1572864;              // 2,555,904 sh (Win pad)
  short* WF1   = WA + 2555904;               // 2,359,296 sh (fc1 interleaved)
  short* WB    = WF1 + 2359296;              // 1,179,648 sh (Wout)
  short* WC    = WB + 1179648;               // 1,179,648 sh (Wfc2)
  short* XTall = WC + 1179648;               // 3,145,728 sh (xs^T; then Hsbf)
  short* BTg   = XTall + 3145728;            // 131,072 sh (B^T)
  short* BCbf  = BTg + 131072;               // 262,144 sh

  short* Hsbf = XTall;                       // overlay: XTall dead after ssd_a
  float* x1   = Sb;                          // overlay: Sb dead after scan2
  short* ybn  = (short*)(Sb + 1572864);
  short* gbf  = zxb;                         // overlay: zx dead after ssd_b

  // 1) all weight casts in one launch
  cast_weights_kernel<<<(T_WINP + T_FC1 + 2 * T_W768 + 255) / 256, 256, 0, stream>>>(
      Win, Wfc1, Wout, Wfc2, WA, WF1, WB, WC);
  // 2) LN1 -> bf16
  ln_kernel<<<SEQ, 256, 0, stream>>>(x, ln1w, ln1b, hbf);
  // 3) in_proj: zx = h @ Win^T  -> bf16
  mfma_gemm_bt<4, 4, 1><<<dim3(26, 16), 256, 0, stream>>>(hbf, WA, zxb, nullptr, SEQ, D_IN_PROJ, D_MODEL);
  // 4) fused conv+silu+pack + dt/la (ct==26)
  conv_pack_kernel<<<dim3(27, 32), 256, 0, stream>>>(zxb, convw, convb, dtb, Alog,
                                                     xsb, XTall, BTg, BCbf, dts, laB);
  // 5) SSD: diag + chunk states, combine, off-diag + gate
  ssd_a_kernel<<<NCHUNK * NHEADS, 256, 0, stream>>>(BCbf, XTall, BTg, laB, dts, ylg, Sb);
  scan2_kernel<<<(NHEADS * 4096) / 256, 256, 0, stream>>>(Sb, laB, Hsbf);
  ssd_b_kernel<<<NCHUNK * NHEADS, 256, 0, stream>>>(BCbf, Hsbf, laB, Dsk, xsb, zxb, ylg);
  // 6) RMSNorm -> bf16
  rmsnorm_bf_kernel<<<SEQ, 256, 0, stream>>>(ylg, nrmw, ybn);
  // 7) out_proj + residual: x1 = x + y @ Wout^T   (64x64 tiles, 384 blocks)
  mfma_gemm_bt<2, 2, 0><<<dim3(12, 32), 256, 0, stream>>>(ybn, WB, x1, x, SEQ, D_MODEL, D_INNER);
  // 8) LN2 -> bf16
  ln_kernel<<<SEQ, 256, 0, stream>>>(x1, ln2w, ln2b, hbf);
  // 9) fc1 (interleaved) + fused GLU -> bf16
  mfma_gemm_bt<4, 4, 2><<<dim3(24, 16), 256, 0, stream>>>(hbf, WF1, gbf, nullptr, SEQ, 2 * HIDDEN, D_MODEL);
  // 10) fc2 + residual: out = x1 + g @ Wfc2^T   (64x64 tiles)
  mfma_gemm_bt<2, 2, 0><<<dim3(12, 32), 256, 0, stream>>>(gbf, WC, out, x1, SEQ, D_MODEL, HIDDEN);
}

// Round 7
// 154.539 us; speedup vs baseline: 5.2426x; 1.1630x over previous
//
#include <hip/hip_runtime.h>
#include <math.h>

#define D_MODEL 768
#define SEQ 2048
#define D_STATE 64
#define D_CONV 4
#define D_INNER 1536
#define HEADDIM 64
#define NHEADS 24
#define CONV_DIM 1664      // D_INNER + 2*D_STATE
#define D_IN_PROJ 3224     // 2*D_INNER + 2*D_STATE + NHEADS
#define HIDDEN 1536
#define EPS 1e-5f
#define NCHUNK 32
#define CHUNK 64

typedef short s16x8 __attribute__((ext_vector_type(8)));
typedef float f32x4 __attribute__((ext_vector_type(4)));

// XOR-swizzled 64-short-stride bf16 tile: row stride 64 shorts (128B), 8-short
// slots, slot ^= (row&7). Involution; b128 reads spread 16 rows -> 2-way (free).
#define SWZ(row, k) (((row) << 6) + ((((k) >> 3) ^ ((row) & 7)) << 3) + ((k) & 7))

// ---------------- helpers ---------------------------------------------------
__device__ __forceinline__ float silu_f(float x) { return x / (1.f + expf(-x)); }

__device__ __forceinline__ short f2bf(float x) {  // RNE fp32 -> bf16 bits
  unsigned u = __builtin_bit_cast(unsigned, x);
  unsigned r = (u + 0x7fffu + ((u >> 16) & 1u)) >> 16;
  return (short)r;
}
__device__ __forceinline__ float bf2f(short s) {
  unsigned u = ((unsigned)(unsigned short)s) << 16;
  return __builtin_bit_cast(float, u);
}

__device__ __forceinline__ float block_sum256(float v, float* sdata) {
#pragma unroll
  for (int o = 32; o > 0; o >>= 1) v += __shfl_down(v, o);
  int lane = threadIdx.x & 63, wid = threadIdx.x >> 6;
  __syncthreads();
  if (lane == 0) sdata[wid] = v;
  __syncthreads();
  if (threadIdx.x == 0) sdata[0] = sdata[0] + sdata[1] + sdata[2] + sdata[3];
  __syncthreads();
  return sdata[0];
}

// async 16B global->LDS (dest: wave-uniform base + lane*16)
__device__ __forceinline__ void gll16(const short* gsrc, const short* ldst) {
  __builtin_amdgcn_global_load_lds(
      (const __attribute__((address_space(1))) unsigned int*)(unsigned long long)gsrc,
      (__attribute__((address_space(3))) unsigned int*)(unsigned int)(unsigned long long)ldst,
      16, 0, 0);
}

// ------- LN row helper (over 768, writes bf16) -------------------------------
__device__ __forceinline__ void ln_row(const float* __restrict__ xr,
                                       const float* __restrict__ w,
                                       const float* __restrict__ b,
                                       short* __restrict__ orow, float* red) {
  float v[3];
#pragma unroll
  for (int k = 0; k < 3; k++) v[k] = xr[threadIdx.x + k * 256];
  float s = v[0] + v[1] + v[2];
  s = block_sum256(s, red);
  float mean = s * (1.f / 768.f);
  float q = 0.f;
#pragma unroll
  for (int k = 0; k < 3; k++) { float d = v[k] - mean; q += d * d; }
  q = block_sum256(q, red);
  float rstd = rsqrtf(q * (1.f / 768.f) + EPS);
#pragma unroll
  for (int k = 0; k < 3; k++) {
    int i = threadIdx.x + k * 256;
    orow[i] = f2bf((v[k] - mean) * rstd * w[i] + b[i]);
  }
}

__global__ __launch_bounds__(256) void ln_kernel(const float* __restrict__ x,
                                                 const float* __restrict__ w,
                                                 const float* __restrict__ b,
                                                 short* __restrict__ out) {
  __shared__ float red[8];
  int row = blockIdx.x;
  ln_row(x + (size_t)row * D_MODEL, w, b, out + (size_t)row * D_MODEL, red);
}

// ------- fused: LN1 (blocks 0..2047) | weight casts (rest) ------------------
#define T_WINP (3328 * 768)
#define R_WINP (3224 * 768)
#define T_FC1 (3072 * 768)
#define T_W768 (1536 * 768)
__global__ __launch_bounds__(256) void cast_ln_kernel(
    const float* __restrict__ x, const float* __restrict__ ln1w,
    const float* __restrict__ ln1b, short* __restrict__ hbf,
    const float* __restrict__ Win, const float* __restrict__ Wfc1,
    const float* __restrict__ Wout, const float* __restrict__ Wfc2,
    short* __restrict__ WA, short* __restrict__ WF1,
    short* __restrict__ WB, short* __restrict__ WC) {
  __shared__ float red[8];
  if (blockIdx.x < SEQ) {
    int row = blockIdx.x;
    ln_row(x + (size_t)row * D_MODEL, ln1w, ln1b, hbf + (size_t)row * D_MODEL, red);
    return;
  }
  int idx = (blockIdx.x - SEQ) * 256 + threadIdx.x;
  if (idx < T_WINP) {
    WA[idx] = (idx < R_WINP) ? f2bf(Win[idx]) : (short)0;
    return;
  }
  idx -= T_WINP;
  if (idx < T_FC1) {  // interleave: dst row 2j=src j, 2j+1=src H+j
    int np = idx / 768, k = idx % 768;
    int srow = (np & 1) ? (HIDDEN + (np >> 1)) : (np >> 1);
    WF1[idx] = f2bf(Wfc1[(size_t)srow * 768 + k]);
    return;
  }
  idx -= T_FC1;
  if (idx < T_W768) { WB[idx] = f2bf(Wout[idx]); return; }
  idx -= T_W768;
  if (idx < T_W768) WC[idx] = f2bf(Wfc2[idx]);
}

// ---------------- bf16 MFMA GEMM: C = A(MxK) * W(NpadxK)^T, BK=64 -----------
// tile = (MREP*32) x (NREP*32); 256 threads = 4 waves (2x2). 1D grid, XCD-
// chunked swizzle: CHUNKMODE 0 = column-chunks (share A), 1 = row-chunks.
// OMODE: 0 = fp32 out (+optional res), 1 = bf16 out, 2 = bf16 GLU-pair out
template <int MREP, int NREP, int CHUNKMODE, int OMODE>
__global__ __launch_bounds__(256) void mfma_gemm_bt(const short* __restrict__ A,
                                                    const short* __restrict__ Bw,
                                                    void* __restrict__ Cout,
                                                    const float* __restrict__ res,
                                                    int GX, int GY, int Nreal, int K) {
  constexpr int BMr = MREP * 32;
  constexpr int BNr = NREP * 32;
  __shared__ short As[BMr * 64];
  __shared__ short Bs[BNr * 64];
  int tid = threadIdx.x, w = tid >> 6, l = tid & 63;
  // bijective XCD swizzle (gridDim.x % 8 == 0 for all call sites)
  int per8 = gridDim.x >> 3;
  int L = (blockIdx.x & 7) * per8 + (blockIdx.x >> 3);
  int xt, yt;
  if constexpr (CHUNKMODE == 0) { xt = L / GY; yt = L - xt * GY; }
  else                          { yt = L / GX; xt = L - yt * GX; }
  int m0 = yt * BMr, n0 = xt * BNr;
  int wr = (w >> 1) * (MREP * 16), wc = (w & 1) * (NREP * 16);
  f32x4 acc[MREP][NREP] = {};

  for (int kt = 0; kt < K; kt += 64) {
    __syncthreads();
    // stage A tile (BMr x 64 bf16): one gll16 issue = 8 rows x 128B
#pragma unroll
    for (int q = 0; q < BMr / 32; q++) {
      int chunk = w * (BMr / 32) + q;
      int rr = chunk * 8 + (l >> 3);
      int gs = (l & 7) ^ (rr & 7);
      gll16(A + (size_t)(m0 + rr) * K + kt + gs * 8, As + chunk * 512);
    }
#pragma unroll
    for (int q = 0; q < BNr / 32; q++) {
      int chunk = w * (BNr / 32) + q;
      int rr = chunk * 8 + (l >> 3);
      int gs = (l & 7) ^ (rr & 7);
      gll16(Bw + (size_t)(n0 + rr) * K + kt + gs * 8, Bs + chunk * 512);
    }
    __syncthreads();
#pragma unroll
    for (int half = 0; half < 2; half++) {
      s16x8 af[MREP], bfr[NREP];
      int kk = half * 32 + (l >> 4) * 8;
#pragma unroll
      for (int mi = 0; mi < MREP; mi++)
        af[mi] = *(const s16x8*)&As[SWZ(wr + mi * 16 + (l & 15), kk)];
#pragma unroll
      for (int nj = 0; nj < NREP; nj++)
        bfr[nj] = *(const s16x8*)&Bs[SWZ(wc + nj * 16 + (l & 15), kk)];
#pragma unroll
      for (int mi = 0; mi < MREP; mi++)
#pragma unroll
        for (int nj = 0; nj < NREP; nj++)
          acc[mi][nj] = __builtin_amdgcn_mfma_f32_16x16x32_bf16(af[mi], bfr[nj],
                                                                acc[mi][nj], 0, 0, 0);
    }
  }
  // epilogue: C/D map col=lane&15, row=(lane>>4)*4+reg  [m89-verified]
#pragma unroll
  for (int mi = 0; mi < MREP; mi++)
#pragma unroll
    for (int nj = 0; nj < NREP; nj++)
#pragma unroll
      for (int r = 0; r < 4; r++) {
        int mm = m0 + wr + mi * 16 + (l >> 4) * 4 + r;
        int nn = n0 + wc + nj * 16 + (l & 15);
        float v = acc[mi][nj][r];
        if constexpr (OMODE == 0) {
          float* C = (float*)Cout;
          if (nn < Nreal) {
            if (res) v += res[(size_t)mm * Nreal + nn];
            C[(size_t)mm * Nreal + nn] = v;
          }
        } else if constexpr (OMODE == 1) {
          short* C = (short*)Cout;
          if (nn < Nreal) C[(size_t)mm * Nreal + nn] = f2bf(v);
        } else {
          // GLU pair: even col = a, odd col = b (partner lane l^1); out = a*silu(b)
          float pv = __shfl_xor(v, 1);
          if ((l & 1) == 0) {
            short* g = (short*)Cout;
            g[(size_t)mm * (Nreal >> 1) + (nn >> 1)] = f2bf(v * silu_f(pv));
          }
        }
      }
}

// ------- fused conv4+SiLU+pack (ct<26) and dt/softplus/la-cumsum (ct==26) ---
__global__ __launch_bounds__(256) void conv_pack_kernel(const short* __restrict__ zx,
                                                        const float* __restrict__ cw,
                                                        const float* __restrict__ cb,
                                                        const float* __restrict__ dtb,
                                                        const float* __restrict__ Alog,
                                                        short* __restrict__ xsb,
                                                        short* __restrict__ XTall,
                                                        short* __restrict__ BTg,
                                                        short* __restrict__ BCbf,
                                                        float* __restrict__ dts,
                                                        float* __restrict__ laB) {
  int ct = blockIdx.x, rt = blockIdx.y;
  if (ct == 26) {  // dt path: chunk rt, 4 waves x 6 heads
    int wv = threadIdx.x >> 6, t = threadIdx.x & 63;
    int gt = rt * 64 + t;
#pragma unroll
    for (int i = 0; i < 6; i++) {
      int h = wv * 6 + i;
      float xv = bf2f(zx[(size_t)gt * D_IN_PROJ + 3200 + h]) + dtb[h];
      float sp = (xv > 20.f) ? xv : log1pf(expf(xv));
      float la = -expf(Alog[h]) * sp;
#pragma unroll
      for (int off = 1; off < 64; off <<= 1) {
        float u = __shfl_up(la, off);
        if (t >= off) la += u;
      }
      dts[gt * NHEADS + h] = sp;
      laB[gt * NHEADS + h] = la;
    }
    return;
  }
  __shared__ float T[64][65];
  int lane = threadIdx.x & 63, grp = threadIdx.x >> 6;
  int c = ct * 64 + lane;
  float4 w4 = *(const float4*)&cw[c * 4];
  float cbv = cb[c];
  int t0 = rt * 64 + grp * 16;
  float vbuf[19];
#pragma unroll
  for (int jj = 0; jj < 19; jj++) {
    int tt = t0 + jj - 3;
    vbuf[jj] = (tt >= 0) ? bf2f(zx[(size_t)tt * D_IN_PROJ + D_INNER + c]) : 0.f;
  }
#pragma unroll
  for (int j = 0; j < 16; j++) {
    float acc = cbv + vbuf[j] * w4.x + vbuf[j + 1] * w4.y +
                vbuf[j + 2] * w4.z + vbuf[j + 3] * w4.w;
    float v = silu_f(acc);
    int row = grp * 16 + j;
    T[row][lane] = v;
    if (ct < 24)
      xsb[(size_t)(rt * 64 + row) * D_INNER + c] = f2bf(v);
    else
      BCbf[(size_t)(rt * 64 + row) * 128 + (ct - 24) * 64 + lane] = f2bf(v);
  }
  __syncthreads();
  if (ct < 24) {
#pragma unroll
    for (int j = 0; j < 16; j++) {
      int cc = grp * 16 + j;
      XTall[(size_t)(ct * 64 + cc) * 2048 + rt * 64 + lane] = f2bf(T[lane][cc]);
    }
  } else if (ct == 24) {
#pragma unroll
    for (int j = 0; j < 16; j++) {
      int cc = grp * 16 + j;
      BTg[(size_t)cc * 2048 + rt * 64 + lane] = f2bf(T[lane][cc]);
    }
  }
}

// ------- SSD-A per (chunk,head): G=C@B^T, M, y_diag=M@X, h_end=(wX)^T@B -----
__global__ __launch_bounds__(256) void ssd_a_kernel(const short* __restrict__ BCbf,
                                                    const short* __restrict__ XTall,
                                                    const short* __restrict__ BTg,
                                                    const float* __restrict__ laB,
                                                    const float* __restrict__ dts,
                                                    short* __restrict__ ylg,
                                                    short* __restrict__ Sbh) {
  __shared__ short Cl[4096], Bl[4096], XTl[4096], BTl[4096], Ml[4096];
  __shared__ float la_s[64], dt_s[64], w_s[64];
  int b = blockIdx.x;
  int c = b / NHEADS, h = b % NHEADS;
  int tid = threadIdx.x, w = tid >> 6, l = tid & 63;

  {
    const short* gC = BCbf + (size_t)(c * 64) * 128 + 64;
    const short* gB = BCbf + (size_t)(c * 64) * 128;
    const short* gX = XTall + (size_t)(h * 64) * 2048 + c * 64;
    const short* gT = BTg + c * 64;
#pragma unroll
    for (int q = 0; q < 2; q++) {
      int row = w * 16 + q * 8 + (l >> 3);
      int ks = (l & 7) ^ (row & 7);
      int lofs = (w * 16 + q * 8) * 64;
      gll16(gC + (size_t)row * 128 + ks * 8, Cl + lofs);
      gll16(gB + (size_t)row * 128 + ks * 8, Bl + lofs);
      gll16(gX + (size_t)row * 2048 + ks * 8, XTl + lofs);
      gll16(gT + (size_t)row * 2048 + ks * 8, BTl + lofs);
    }
  }
  if (tid < 64) {
    la_s[tid] = laB[(c * CHUNK + tid) * NHEADS + h];
    dt_s[tid] = dts[(c * CHUNK + tid) * NHEADS + h];
  }
  __syncthreads();

  // G = C @ B^T
  f32x4 gacc[4] = {};
#pragma unroll
  for (int kt = 0; kt < 2; kt++) {
    int ar = w * 16 + (l & 15);
    int kk = kt * 32 + (l >> 4) * 8;
    s16x8 af = *(const s16x8*)&Cl[SWZ(ar, kk)];
#pragma unroll
    for (int nj = 0; nj < 4; nj++) {
      s16x8 bf_ = *(const s16x8*)&Bl[SWZ(nj * 16 + (l & 15), kk)];
      gacc[nj] = __builtin_amdgcn_mfma_f32_16x16x32_bf16(af, bf_, gacc[nj], 0, 0, 0);
    }
  }
  if (tid < 64) w_s[tid] = __expf(la_s[63] - la_s[tid]) * dt_s[tid];
  // M[t,s] = G * exp(la_t - la_s) * dt_s  (s<=t)
#pragma unroll
  for (int nj = 0; nj < 4; nj++)
#pragma unroll
    for (int r = 0; r < 4; r++) {
      int t = w * 16 + (l >> 4) * 4 + r;
      int s = nj * 16 + (l & 15);
      float m = (s <= t) ? gacc[nj][r] * __expf(la_s[t] - la_s[s]) * dt_s[s] : 0.f;
      Ml[SWZ(t, s)] = f2bf(m);
    }
  __syncthreads();
  // scale BTl[s][t] *= w[t]
  {
    int s = tid & 63, tg = (tid >> 6) * 16;
#pragma unroll
    for (int j = 0; j < 16; j++) {
      int t = tg + j;
      int a = SWZ(s, t);
      BTl[a] = f2bf(bf2f(BTl[a]) * w_s[t]);
    }
  }
  __syncthreads();

  // y_diag[t,p] = sum_s M[t,s] * XT[p,s]
  f32x4 yacc[4] = {};
#pragma unroll
  for (int kt = 0; kt < 2; kt++) {
    int ar = w * 16 + (l & 15);
    int kk = kt * 32 + (l >> 4) * 8;
    s16x8 af = *(const s16x8*)&Ml[SWZ(ar, kk)];
#pragma unroll
    for (int nj = 0; nj < 4; nj++) {
      s16x8 bf_ = *(const s16x8*)&XTl[SWZ(nj * 16 + (l & 15), kk)];
      yacc[nj] = __builtin_amdgcn_mfma_f32_16x16x32_bf16(af, bf_, yacc[nj], 0, 0, 0);
    }
  }
  // h_end[p,s] = sum_t XT[p,t]*w[t]*B[t,s]
  f32x4 hacc[4] = {};
#pragma unroll
  for (int kt = 0; kt < 2; kt++) {
    int ar = w * 16 + (l & 15);
    int kk = kt * 32 + (l >> 4) * 8;
    s16x8 af = *(const s16x8*)&XTl[SWZ(ar, kk)];
#pragma unroll
    for (int nj = 0; nj < 4; nj++) {
      s16x8 bf_ = *(const s16x8*)&BTl[SWZ(nj * 16 + (l & 15), kk)];
      hacc[nj] = __builtin_amdgcn_mfma_f32_16x16x32_bf16(af, bf_, hacc[nj], 0, 0, 0);
    }
  }
#pragma unroll
  for (int nj = 0; nj < 4; nj++)
#pragma unroll
    for (int r = 0; r < 4; r++) {
      int t = w * 16 + (l >> 4) * 4 + r;
      int p = nj * 16 + (l & 15);
      ylg[(size_t)(c * CHUNK + t) * D_INNER + h * 64 + p] = f2bf(yacc[nj][r]);
      Sbh[((size_t)(c * NHEADS + h) * 64 + t) * 64 + p] = f2bf(hacc[nj][r]);
    }
}

// ---- scan pass 2: chunk combine (bf16 in); emits h_start bf16 (Hsbf) -------
__global__ __launch_bounds__(256) void scan2_kernel(const short* __restrict__ Sbh,
                                                    const float* __restrict__ laB,
                                                    short* __restrict__ Hsbf) {
  int idx = blockIdx.x * 256 + threadIdx.x;  // [0, 24*4096)
  int hh = idx >> 12;
  int rem = idx & 4095;  // p*64 + s
  float Sv[NCHUNK];
#pragma unroll
  for (int c = 0; c < NCHUNK; c++)
    Sv[c] = bf2f(Sbh[((size_t)c * NHEADS + hh) * 4096 + rem]);
  float run = 0.f;
#pragma unroll
  for (int c = 0; c < NCHUNK; c++) {
    float P = __expf(laB[(c * CHUNK + CHUNK - 1) * NHEADS + hh]);
    Hsbf[((size_t)c * NHEADS + hh) * 4096 + rem] = f2bf(run);
    run = fmaf(P, run, Sv[c]);
  }
}

// ------- SSD-B per (chunk,head): y += exp(la_t)*C@h_start^T + D*xs; gate ----
__global__ __launch_bounds__(256) void ssd_b_kernel(const short* __restrict__ BCbf,
                                                    const short* __restrict__ Hsbf,
                                                    const float* __restrict__ laB,
                                                    const float* __restrict__ Dsk,
                                                    const short* __restrict__ xsb,
                                                    const short* __restrict__ zx,
                                                    short* __restrict__ ylg) {
  __shared__ short Cl[4096], Hl[4096];
  __shared__ float la_s[64];
  int b = blockIdx.x;
  int c = b / NHEADS, h = b % NHEADS;
  int tid = threadIdx.x, w = tid >> 6, l = tid & 63;
  {
    const short* gC = BCbf + (size_t)(c * 64) * 128 + 64;
    const short* gH = Hsbf + (size_t)(c * NHEADS + h) * 4096;
#pragma unroll
    for (int q = 0; q < 2; q++) {
      int row = w * 16 + q * 8 + (l >> 3);
      int ks = (l & 7) ^ (row & 7);
      int lofs = (w * 16 + q * 8) * 64;
      gll16(gC + (size_t)row * 128 + ks * 8, Cl + lofs);
      gll16(gH + (size_t)row * 64 + ks * 8, Hl + lofs);
    }
  }
  if (tid < 64) la_s[tid] = laB[(c * CHUNK + tid) * NHEADS + h];
  __syncthreads();
  f32x4 acc[4] = {};
#pragma unroll
  for (int kt = 0; kt < 2; kt++) {
    int ar = w * 16 + (l & 15);
    int kk = kt * 32 + (l >> 4) * 8;
    s16x8 af = *(const s16x8*)&Cl[SWZ(ar, kk)];
#pragma unroll
    for (int nj = 0; nj < 4; nj++) {
      s16x8 bf_ = *(const s16x8*)&Hl[SWZ(nj * 16 + (l & 15), kk)];
      acc[nj] = __builtin_amdgcn_mfma_f32_16x16x32_bf16(af, bf_, acc[nj], 0, 0, 0);
    }
  }
  float Dv = Dsk[h];
#pragma unroll
  for (int nj = 0; nj < 4; nj++)
#pragma unroll
    for (int r = 0; r < 4; r++) {
      int t = w * 16 + (l >> 4) * 4 + r;
      int p = nj * 16 + (l & 15);
      size_t gt = c * CHUNK + t;
      size_t gi = gt * D_INNER + h * 64 + p;
      float yv = bf2f(ylg[gi]) + acc[nj][r] * __expf(la_s[t]) +
                 Dv * bf2f(xsb[gt * D_INNER + h * 64 + p]);
      float z = bf2f(zx[gt * D_IN_PROJ + h * 64 + p]);
      ylg[gi] = f2bf(yv * silu_f(z));
    }
}

// ---------------- RMSNorm over D_INNER (bf16 in), writes bf16 ---------------
__global__ __launch_bounds__(256) void rmsnorm_bf_kernel(const short* __restrict__ g,
                                                         const float* __restrict__ nw,
                                                         short* __restrict__ ybn) {
  __shared__ float red[8];
  int t = blockIdx.x;
  const short* gr = g + (size_t)t * D_INNER;
  float v[6];
  float ss = 0.f;
#pragma unroll
  for (int k = 0; k < 6; k++) {
    v[k] = bf2f(gr[threadIdx.x + k * 256]);
    ss += v[k] * v[k];
  }
  ss = block_sum256(ss, red);
  float rs = rsqrtf(ss * (1.f / (float)D_INNER) + EPS);
  short* orow = ybn + (size_t)t * D_INNER;
#pragma unroll
  for (int k = 0; k < 6; k++) {
    int i = threadIdx.x + k * 256;
    orow[i] = f2bf(v[k] * rs * nw[i]);
  }
}

// ----------------------------------------------------------------------------
extern "C" void kernel_launch(void* const* d_in, const int* in_sizes, int n_in,
                              void* d_out, int out_size, void* d_ws, size_t ws_size,
                              hipStream_t stream) {
  const float* x     = (const float*)d_in[0];
  const float* ln1w  = (const float*)d_in[1];
  const float* ln1b  = (const float*)d_in[2];
  const float* ln2w  = (const float*)d_in[3];
  const float* ln2b  = (const float*)d_in[4];
  const float* Win   = (const float*)d_in[5];
  const float* convw = (const float*)d_in[6];
  const float* convb = (const float*)d_in[7];
  const float* dtb   = (const float*)d_in[8];
  const float* Alog  = (const float*)d_in[9];
  const float* Dsk   = (const float*)d_in[10];
  const float* nrmw  = (const float*)d_in[11];
  const float* Wout  = (const float*)d_in[12];
  const float* Wfc1  = (const float*)d_in[13];
  const float* Wfc2  = (const float*)d_in[14];
  float* out = (float*)d_out;

  // ---- workspace layout (~64 MB) ----
  short* zxb   = (short*)d_ws;               // 6,602,752 sh (bf16 zx; reused: gbf)
  short* xsb   = zxb + 6602752;              // 3,145,728 sh
  short* ylg   = xsb + 3145728;              // 3,145,728 sh
  float* Sbf   = (float*)(ylg + 3145728);    // 3,145,728 f region (Sbh; then x1+ybn)
  float* dts   = Sbf + 3145728;              // 49,152 f
  float* laB   = dts + 49152;                // 49,152 f
  short* hbf   = (short*)(laB + 49152);      // 1,572,864 sh
  short* WA    = hbf + 1572864;              // 2,555,904 sh (Win pad)
  short* WF1   = WA + 2555904;               // 2,359,296 sh (fc1 interleaved)
  short* WB    = WF1 + 2359296;              // 1,179,648 sh (Wout)
  short* WC    = WB + 1179648;               // 1,179,648 sh (Wfc2)
  short* XTall = WC + 1179648;               // 3,145,728 sh (xs^T; then Hsbf)
  short* BTg   = XTall + 3145728;            // 131,072 sh (B^T)
  short* BCbf  = BTg + 131072;               // 262,144 sh

  short* Sbh  = (short*)Sbf;                 // bf16 chunk states (6.3MB of region)
  short* Hsbf = XTall;                       // overlay: XTall dead after ssd_a
  float* x1   = Sbf;                         // overlay: Sbh dead after scan2
  short* ybn  = (short*)(Sbf + 1572864);
  short* gbf  = zxb;                         // overlay: zx dead after ssd_b

  // 1) LN1 + all weight casts in one launch
  cast_ln_kernel<<<SEQ + (T_WINP + T_FC1 + 2 * T_W768 + 255) / 256, 256, 0, stream>>>(
      x, ln1w, ln1b, hbf, Win, Wfc1, Wout, Wfc2, WA, WF1, WB, WC);
  // 2) in_proj: zx = h @ Win^T -> bf16 (128x128 tiles, col-chunk swizzle)
  mfma_gemm_bt<4, 4, 0, 1><<<26 * 16, 256, 0, stream>>>(hbf, WA, zxb, nullptr,
                                                        26, 16, D_IN_PROJ, D_MODEL);
  // 3) fused conv+silu+pack + dt/la (ct==26)
  conv_pack_kernel<<<dim3(27, 32), 256, 0, stream>>>(zxb, convw, convb, dtb, Alog,
                                                     xsb, XTall, BTg, BCbf, dts, laB);
  // 4) SSD: diag + chunk states, combine, off-diag + gate
  ssd_a_kernel<<<NCHUNK * NHEADS, 256, 0, stream>>>(BCbf, XTall, BTg, laB, dts, ylg, Sbh);
  scan2_kernel<<<(NHEADS * 4096) / 256, 256, 0, stream>>>(Sbh, laB, Hsbf);
  ssd_b_kernel<<<NCHUNK * NHEADS, 256, 0, stream>>>(BCbf, Hsbf, laB, Dsk, xsb, zxb, ylg);
  // 5) RMSNorm -> bf16
  rmsnorm_bf_kernel<<<SEQ, 256, 0, stream>>>(ylg, nrmw, ybn);
  // 6) out_proj + residual: x1 = x + y @ Wout^T (64x64 tiles, row-chunk swizzle)
  mfma_gemm_bt<2, 2, 1, 0><<<12 * 32, 256, 0, stream>>>(ybn, WB, x1, x,
                                                        12, 32, D_MODEL, D_INNER);
  // 7) LN2 -> bf16
  ln_kernel<<<SEQ, 256, 0, stream>>>(x1, ln2w, ln2b, hbf);
  // 8) fc1 (interleaved) + fused GLU -> bf16 (col-chunk swizzle)
  mfma_gemm_bt<4, 4, 0, 2><<<24 * 16, 256, 0, stream>>>(hbf, WF1, gbf, nullptr,
                                                        24, 16, 2 * HIDDEN, D_MODEL);
  // 9) fc2 + residual: out = x1 + g @ Wfc2^T (row-chunk swizzle)
  mfma_gemm_bt<2, 2, 1, 0><<<12 * 32, 256, 0, stream>>>(gbf, WC, out, x1,
                                                        12, 32, D_MODEL, HIDDEN);
}

// Round 8
// 151.367 us; speedup vs baseline: 5.3525x; 1.0210x over previous
//
#include <hip/hip_runtime.h>
#include <math.h>

#define D_MODEL 768
#define SEQ 2048
#define D_STATE 64
#define D_CONV 4
#define D_INNER 1536
#define HEADDIM 64
#define NHEADS 24
#define CONV_DIM 1664      // D_INNER + 2*D_STATE
#define D_IN_PROJ 3224     // 2*D_INNER + 2*D_STATE + NHEADS
#define HIDDEN 1536
#define EPS 1e-5f
#define NCHUNK 32
#define CHUNK 64

typedef short s16x8 __attribute__((ext_vector_type(8)));
typedef float f32x4 __attribute__((ext_vector_type(4)));

// XOR-swizzled 64-short-stride bf16 tile: row stride 64 shorts (128B), 8-short
// slots, slot ^= (row&7). Involution; b128 reads spread 16 rows -> 2-way (free).
#define SWZ(row, k) (((row) << 6) + ((((k) >> 3) ^ ((row) & 7)) << 3) + ((k) & 7))

// ---------------- helpers ---------------------------------------------------
__device__ __forceinline__ float silu_f(float x) { return x / (1.f + expf(-x)); }

__device__ __forceinline__ short f2bf(float x) {  // RNE fp32 -> bf16 bits
  unsigned u = __builtin_bit_cast(unsigned, x);
  unsigned r = (u + 0x7fffu + ((u >> 16) & 1u)) >> 16;
  return (short)r;
}
__device__ __forceinline__ float bf2f(short s) {
  unsigned u = ((unsigned)(unsigned short)s) << 16;
  return __builtin_bit_cast(float, u);
}

__device__ __forceinline__ float block_sum256(float v, float* sdata) {
#pragma unroll
  for (int o = 32; o > 0; o >>= 1) v += __shfl_down(v, o);
  int lane = threadIdx.x & 63, wid = threadIdx.x >> 6;
  __syncthreads();
  if (lane == 0) sdata[wid] = v;
  __syncthreads();
  if (threadIdx.x == 0) sdata[0] = sdata[0] + sdata[1] + sdata[2] + sdata[3];
  __syncthreads();
  return sdata[0];
}

// async 16B global->LDS (dest: wave-uniform base + lane*16)
__device__ __forceinline__ void gll16(const short* gsrc, const short* ldst) {
  __builtin_amdgcn_global_load_lds(
      (const __attribute__((address_space(1))) unsigned int*)(unsigned long long)gsrc,
      (__attribute__((address_space(3))) unsigned int*)(unsigned int)(unsigned long long)ldst,
      16, 0, 0);
}

// ------- LN row helper (over 768, writes bf16) -------------------------------
__device__ __forceinline__ void ln_row(const float* __restrict__ xr,
                                       const float* __restrict__ w,
                                       const float* __restrict__ b,
                                       short* __restrict__ orow, float* red) {
  float v[3];
#pragma unroll
  for (int k = 0; k < 3; k++) v[k] = xr[threadIdx.x + k * 256];
  float s = v[0] + v[1] + v[2];
  s = block_sum256(s, red);
  float mean = s * (1.f / 768.f);
  float q = 0.f;
#pragma unroll
  for (int k = 0; k < 3; k++) { float d = v[k] - mean; q += d * d; }
  q = block_sum256(q, red);
  float rstd = rsqrtf(q * (1.f / 768.f) + EPS);
#pragma unroll
  for (int k = 0; k < 3; k++) {
    int i = threadIdx.x + k * 256;
    orow[i] = f2bf((v[k] - mean) * rstd * w[i] + b[i]);
  }
}

__global__ __launch_bounds__(256) void ln_kernel(const float* __restrict__ x,
                                                 const float* __restrict__ w,
                                                 const float* __restrict__ b,
                                                 short* __restrict__ out) {
  __shared__ float red[8];
  int row = blockIdx.x;
  ln_row(x + (size_t)row * D_MODEL, w, b, out + (size_t)row * D_MODEL, red);
}

// ------- fused: LN1 (blocks 0..2047) | weight casts (rest) ------------------
// Wout cast has ssm_norm_w folded into its columns (RMSNorm factorization).
#define T_WINP (3328 * 768)
#define R_WINP (3224 * 768)
#define T_FC1 (3072 * 768)
#define T_W768 (1536 * 768)
__global__ __launch_bounds__(256) void cast_ln_kernel(
    const float* __restrict__ x, const float* __restrict__ ln1w,
    const float* __restrict__ ln1b, short* __restrict__ hbf,
    const float* __restrict__ Win, const float* __restrict__ Wfc1,
    const float* __restrict__ Wout, const float* __restrict__ Wfc2,
    const float* __restrict__ nrmw,
    short* __restrict__ WA, short* __restrict__ WF1,
    short* __restrict__ WB, short* __restrict__ WC) {
  __shared__ float red[8];
  if (blockIdx.x < SEQ) {
    int row = blockIdx.x;
    ln_row(x + (size_t)row * D_MODEL, ln1w, ln1b, hbf + (size_t)row * D_MODEL, red);
    return;
  }
  int idx = (blockIdx.x - SEQ) * 256 + threadIdx.x;
  if (idx < T_WINP) {
    WA[idx] = (idx < R_WINP) ? f2bf(Win[idx]) : (short)0;
    return;
  }
  idx -= T_WINP;
  if (idx < T_FC1) {  // interleave: dst row 2j=src j, 2j+1=src H+j
    int np = idx / 768, k = idx % 768;
    int srow = (np & 1) ? (HIDDEN + (np >> 1)) : (np >> 1);
    WF1[idx] = f2bf(Wfc1[(size_t)srow * 768 + k]);
    return;
  }
  idx -= T_FC1;
  if (idx < T_W768) {  // fold ssm_norm_w into Wout columns
    WB[idx] = f2bf(Wout[idx] * nrmw[idx % D_INNER]);
    return;
  }
  idx -= T_W768;
  if (idx < T_W768) WC[idx] = f2bf(Wfc2[idx]);
}

// ---------------- bf16 MFMA GEMM: C = A(MxK) * W(NpadxK)^T, BK=64 -----------
// tile = (MREP*32) x (NREP*32); 256 threads = 4 waves (2x2). 1D grid, XCD-
// chunked swizzle: CHUNKMODE 0 = column-chunks (share A), 1 = row-chunks.
// OMODE: 0 = fp32 out (+res), 1 = bf16 out, 2 = bf16 GLU-pair out,
//        3 = fp32 out with per-row rs = rsqrt(mean(ssqp)+eps) scaling (+res)
template <int MREP, int NREP, int CHUNKMODE, int OMODE>
__global__ __launch_bounds__(256) void mfma_gemm_bt(const short* __restrict__ A,
                                                    const short* __restrict__ Bw,
                                                    void* __restrict__ Cout,
                                                    const float* __restrict__ res,
                                                    const float* __restrict__ ssqp,
                                                    int GX, int GY, int Nreal, int K) {
  constexpr int BMr = MREP * 32;
  constexpr int BNr = NREP * 32;
  __shared__ short As[BMr * 64];
  __shared__ short Bs[BNr * 64];
  __shared__ float rs_s[BMr];
  int tid = threadIdx.x, w = tid >> 6, l = tid & 63;
  // bijective XCD swizzle (gridDim.x % 8 == 0 for all call sites)
  int per8 = gridDim.x >> 3;
  int L = (blockIdx.x & 7) * per8 + (blockIdx.x >> 3);
  int xt, yt;
  if constexpr (CHUNKMODE == 0) { xt = L / GY; yt = L - xt * GY; }
  else                          { yt = L / GX; xt = L - yt * GX; }
  int m0 = yt * BMr, n0 = xt * BNr;
  int wr = (w >> 1) * (MREP * 16), wc = (w & 1) * (NREP * 16);
  f32x4 acc[MREP][NREP] = {};

  if constexpr (OMODE == 3) {
    if (tid < BMr) {
      const float* sp = ssqp + (size_t)(m0 + tid) * NHEADS;
      float s = 0.f;
#pragma unroll
      for (int i = 0; i < NHEADS; i++) s += sp[i];
      rs_s[tid] = rsqrtf(s * (1.f / (float)D_INNER) + EPS);
    }
  }

  for (int kt = 0; kt < K; kt += 64) {
    __syncthreads();
    // stage A tile (BMr x 64 bf16): one gll16 issue = 8 rows x 128B
#pragma unroll
    for (int q = 0; q < BMr / 32; q++) {
      int chunk = w * (BMr / 32) + q;
      int rr = chunk * 8 + (l >> 3);
      int gs = (l & 7) ^ (rr & 7);
      gll16(A + (size_t)(m0 + rr) * K + kt + gs * 8, As + chunk * 512);
    }
#pragma unroll
    for (int q = 0; q < BNr / 32; q++) {
      int chunk = w * (BNr / 32) + q;
      int rr = chunk * 8 + (l >> 3);
      int gs = (l & 7) ^ (rr & 7);
      gll16(Bw + (size_t)(n0 + rr) * K + kt + gs * 8, Bs + chunk * 512);
    }
    __syncthreads();
#pragma unroll
    for (int half = 0; half < 2; half++) {
      s16x8 af[MREP], bfr[NREP];
      int kk = half * 32 + (l >> 4) * 8;
#pragma unroll
      for (int mi = 0; mi < MREP; mi++)
        af[mi] = *(const s16x8*)&As[SWZ(wr + mi * 16 + (l & 15), kk)];
#pragma unroll
      for (int nj = 0; nj < NREP; nj++)
        bfr[nj] = *(const s16x8*)&Bs[SWZ(wc + nj * 16 + (l & 15), kk)];
#pragma unroll
      for (int mi = 0; mi < MREP; mi++)
#pragma unroll
        for (int nj = 0; nj < NREP; nj++)
          acc[mi][nj] = __builtin_amdgcn_mfma_f32_16x16x32_bf16(af[mi], bfr[nj],
                                                                acc[mi][nj], 0, 0, 0);
    }
  }
  // epilogue: C/D map col=lane&15, row=(lane>>4)*4+reg  [m89-verified]
#pragma unroll
  for (int mi = 0; mi < MREP; mi++)
#pragma unroll
    for (int nj = 0; nj < NREP; nj++)
#pragma unroll
      for (int r = 0; r < 4; r++) {
        int lr = wr + mi * 16 + (l >> 4) * 4 + r;
        int mm = m0 + lr;
        int nn = n0 + wc + nj * 16 + (l & 15);
        float v = acc[mi][nj][r];
        if constexpr (OMODE == 0) {
          float* C = (float*)Cout;
          if (nn < Nreal) {
            if (res) v += res[(size_t)mm * Nreal + nn];
            C[(size_t)mm * Nreal + nn] = v;
          }
        } else if constexpr (OMODE == 1) {
          short* C = (short*)Cout;
          if (nn < Nreal) C[(size_t)mm * Nreal + nn] = f2bf(v);
        } else if constexpr (OMODE == 2) {
          // GLU pair: even col = a, odd col = b (partner lane l^1); out = a*silu(b)
          float pv = __shfl_xor(v, 1);
          if ((l & 1) == 0) {
            short* g = (short*)Cout;
            g[(size_t)mm * (Nreal >> 1) + (nn >> 1)] = f2bf(v * silu_f(pv));
          }
        } else {
          float* C = (float*)Cout;
          if (nn < Nreal) {
            v = v * rs_s[lr] + res[(size_t)mm * Nreal + nn];
            C[(size_t)mm * Nreal + nn] = v;
          }
        }
      }
}

// ------- fused conv4+SiLU+pack (ct<26) and dt/softplus/la-cumsum (ct==26) ---
__global__ __launch_bounds__(256) void conv_pack_kernel(const short* __restrict__ zx,
                                                        const float* __restrict__ cw,
                                                        const float* __restrict__ cb,
                                                        const float* __restrict__ dtb,
                                                        const float* __restrict__ Alog,
                                                        short* __restrict__ xsb,
                                                        short* __restrict__ XTall,
                                                        short* __restrict__ BTg,
                                                        short* __restrict__ BCbf,
                                                        float* __restrict__ dts,
                                                        float* __restrict__ laB) {
  int ct = blockIdx.x, rt = blockIdx.y;
  if (ct == 26) {  // dt path: chunk rt, 4 waves x 6 heads
    int wv = threadIdx.x >> 6, t = threadIdx.x & 63;
    int gt = rt * 64 + t;
#pragma unroll
    for (int i = 0; i < 6; i++) {
      int h = wv * 6 + i;
      float xv = bf2f(zx[(size_t)gt * D_IN_PROJ + 3200 + h]) + dtb[h];
      float sp = (xv > 20.f) ? xv : log1pf(expf(xv));
      float la = -expf(Alog[h]) * sp;
#pragma unroll
      for (int off = 1; off < 64; off <<= 1) {
        float u = __shfl_up(la, off);
        if (t >= off) la += u;
      }
      dts[gt * NHEADS + h] = sp;
      laB[gt * NHEADS + h] = la;
    }
    return;
  }
  __shared__ float T[64][65];
  int lane = threadIdx.x & 63, grp = threadIdx.x >> 6;
  int c = ct * 64 + lane;
  float4 w4 = *(const float4*)&cw[c * 4];
  float cbv = cb[c];
  int t0 = rt * 64 + grp * 16;
  float vbuf[19];
#pragma unroll
  for (int jj = 0; jj < 19; jj++) {
    int tt = t0 + jj - 3;
    vbuf[jj] = (tt >= 0) ? bf2f(zx[(size_t)tt * D_IN_PROJ + D_INNER + c]) : 0.f;
  }
#pragma unroll
  for (int j = 0; j < 16; j++) {
    float acc = cbv + vbuf[j] * w4.x + vbuf[j + 1] * w4.y +
                vbuf[j + 2] * w4.z + vbuf[j + 3] * w4.w;
    float v = silu_f(acc);
    int row = grp * 16 + j;
    T[row][lane] = v;
    if (ct < 24)
      xsb[(size_t)(rt * 64 + row) * D_INNER + c] = f2bf(v);
    else
      BCbf[(size_t)(rt * 64 + row) * 128 + (ct - 24) * 64 + lane] = f2bf(v);
  }
  __syncthreads();
  if (ct < 24) {
#pragma unroll
    for (int j = 0; j < 16; j++) {
      int cc = grp * 16 + j;
      XTall[(size_t)(ct * 64 + cc) * 2048 + rt * 64 + lane] = f2bf(T[lane][cc]);
    }
  } else if (ct == 24) {
#pragma unroll
    for (int j = 0; j < 16; j++) {
      int cc = grp * 16 + j;
      BTg[(size_t)cc * 2048 + rt * 64 + lane] = f2bf(T[lane][cc]);
    }
  }
}

// ------- SSD-A per (chunk,head): G=C@B^T, M, y_diag=M@X, h_end=(wX)^T@B -----
__global__ __launch_bounds__(256) void ssd_a_kernel(const short* __restrict__ BCbf,
                                                    const short* __restrict__ XTall,
                                                    const short* __restrict__ BTg,
                                                    const float* __restrict__ laB,
                                                    const float* __restrict__ dts,
                                                    short* __restrict__ ylg,
                                                    short* __restrict__ Sbh) {
  __shared__ short Cl[4096], Bl[4096], XTl[4096], BTl[4096], Ml[4096];
  __shared__ float la_s[64], dt_s[64], w_s[64];
  int b = blockIdx.x;
  int c = b / NHEADS, h = b % NHEADS;
  int tid = threadIdx.x, w = tid >> 6, l = tid & 63;

  {
    const short* gC = BCbf + (size_t)(c * 64) * 128 + 64;
    const short* gB = BCbf + (size_t)(c * 64) * 128;
    const short* gX = XTall + (size_t)(h * 64) * 2048 + c * 64;
    const short* gT = BTg + c * 64;
#pragma unroll
    for (int q = 0; q < 2; q++) {
      int row = w * 16 + q * 8 + (l >> 3);
      int ks = (l & 7) ^ (row & 7);
      int lofs = (w * 16 + q * 8) * 64;
      gll16(gC + (size_t)row * 128 + ks * 8, Cl + lofs);
      gll16(gB + (size_t)row * 128 + ks * 8, Bl + lofs);
      gll16(gX + (size_t)row * 2048 + ks * 8, XTl + lofs);
      gll16(gT + (size_t)row * 2048 + ks * 8, BTl + lofs);
    }
  }
  if (tid < 64) {
    la_s[tid] = laB[(c * CHUNK + tid) * NHEADS + h];
    dt_s[tid] = dts[(c * CHUNK + tid) * NHEADS + h];
  }
  __syncthreads();

  // G = C @ B^T
  f32x4 gacc[4] = {};
#pragma unroll
  for (int kt = 0; kt < 2; kt++) {
    int ar = w * 16 + (l & 15);
    int kk = kt * 32 + (l >> 4) * 8;
    s16x8 af = *(const s16x8*)&Cl[SWZ(ar, kk)];
#pragma unroll
    for (int nj = 0; nj < 4; nj++) {
      s16x8 bf_ = *(const s16x8*)&Bl[SWZ(nj * 16 + (l & 15), kk)];
      gacc[nj] = __builtin_amdgcn_mfma_f32_16x16x32_bf16(af, bf_, gacc[nj], 0, 0, 0);
    }
  }
  if (tid < 64) w_s[tid] = __expf(la_s[63] - la_s[tid]) * dt_s[tid];
  // M[t,s] = G * exp(la_t - la_s) * dt_s  (s<=t)
#pragma unroll
  for (int nj = 0; nj < 4; nj++)
#pragma unroll
    for (int r = 0; r < 4; r++) {
      int t = w * 16 + (l >> 4) * 4 + r;
      int s = nj * 16 + (l & 15);
      float m = (s <= t) ? gacc[nj][r] * __expf(la_s[t] - la_s[s]) * dt_s[s] : 0.f;
      Ml[SWZ(t, s)] = f2bf(m);
    }
  __syncthreads();
  // scale BTl[s][t] *= w[t]
  {
    int s = tid & 63, tg = (tid >> 6) * 16;
#pragma unroll
    for (int j = 0; j < 16; j++) {
      int t = tg + j;
      int a = SWZ(s, t);
      BTl[a] = f2bf(bf2f(BTl[a]) * w_s[t]);
    }
  }
  __syncthreads();

  // y_diag[t,p] = sum_s M[t,s] * XT[p,s]
  f32x4 yacc[4] = {};
#pragma unroll
  for (int kt = 0; kt < 2; kt++) {
    int ar = w * 16 + (l & 15);
    int kk = kt * 32 + (l >> 4) * 8;
    s16x8 af = *(const s16x8*)&Ml[SWZ(ar, kk)];
#pragma unroll
    for (int nj = 0; nj < 4; nj++) {
      s16x8 bf_ = *(const s16x8*)&XTl[SWZ(nj * 16 + (l & 15), kk)];
      yacc[nj] = __builtin_amdgcn_mfma_f32_16x16x32_bf16(af, bf_, yacc[nj], 0, 0, 0);
    }
  }
  // h_end[p,s] = sum_t XT[p,t]*w[t]*B[t,s]
  f32x4 hacc[4] = {};
#pragma unroll
  for (int kt = 0; kt < 2; kt++) {
    int ar = w * 16 + (l & 15);
    int kk = kt * 32 + (l >> 4) * 8;
    s16x8 af = *(const s16x8*)&XTl[SWZ(ar, kk)];
#pragma unroll
    for (int nj = 0; nj < 4; nj++) {
      s16x8 bf_ = *(const s16x8*)&BTl[SWZ(nj * 16 + (l & 15), kk)];
      hacc[nj] = __builtin_amdgcn_mfma_f32_16x16x32_bf16(af, bf_, hacc[nj], 0, 0, 0);
    }
  }
#pragma unroll
  for (int nj = 0; nj < 4; nj++)
#pragma unroll
    for (int r = 0; r < 4; r++) {
      int t = w * 16 + (l >> 4) * 4 + r;
      int p = nj * 16 + (l & 15);
      ylg[(size_t)(c * CHUNK + t) * D_INNER + h * 64 + p] = f2bf(yacc[nj][r]);
      Sbh[((size_t)(c * NHEADS + h) * 64 + t) * 64 + p] = f2bf(hacc[nj][r]);
    }
}

// ---- scan pass 2: chunk combine (bf16 in); emits h_start bf16 (Hsbf) -------
__global__ __launch_bounds__(256) void scan2_kernel(const short* __restrict__ Sbh,
                                                    const float* __restrict__ laB,
                                                    short* __restrict__ Hsbf) {
  int idx = blockIdx.x * 256 + threadIdx.x;  // [0, 24*4096)
  int hh = idx >> 12;
  int rem = idx & 4095;  // p*64 + s
  float Sv[NCHUNK];
#pragma unroll
  for (int c = 0; c < NCHUNK; c++)
    Sv[c] = bf2f(Sbh[((size_t)c * NHEADS + hh) * 4096 + rem]);
  float run = 0.f;
#pragma unroll
  for (int c = 0; c < NCHUNK; c++) {
    float P = __expf(laB[(c * CHUNK + CHUNK - 1) * NHEADS + hh]);
    Hsbf[((size_t)c * NHEADS + hh) * 4096 + rem] = f2bf(run);
    run = fmaf(P, run, Sv[c]);
  }
}

// --- SSD-B per (chunk,head): y += exp(la_t)*C@h_start^T + D*xs; gate;
//     emit per-(t,h) sum-of-squares partials for the fused RMSNorm -----------
__global__ __launch_bounds__(256) void ssd_b_kernel(const short* __restrict__ BCbf,
                                                    const short* __restrict__ Hsbf,
                                                    const float* __restrict__ laB,
                                                    const float* __restrict__ Dsk,
                                                    const short* __restrict__ xsb,
                                                    const short* __restrict__ zx,
                                                    short* __restrict__ ylg,
                                                    float* __restrict__ ssqp) {
  __shared__ short Cl[4096], Hl[4096];
  __shared__ float la_s[64];
  int b = blockIdx.x;
  int c = b / NHEADS, h = b % NHEADS;
  int tid = threadIdx.x, w = tid >> 6, l = tid & 63;
  {
    const short* gC = BCbf + (size_t)(c * 64) * 128 + 64;
    const short* gH = Hsbf + (size_t)(c * NHEADS + h) * 4096;
#pragma unroll
    for (int q = 0; q < 2; q++) {
      int row = w * 16 + q * 8 + (l >> 3);
      int ks = (l & 7) ^ (row & 7);
      int lofs = (w * 16 + q * 8) * 64;
      gll16(gC + (size_t)row * 128 + ks * 8, Cl + lofs);
      gll16(gH + (size_t)row * 64 + ks * 8, Hl + lofs);
    }
  }
  if (tid < 64) la_s[tid] = laB[(c * CHUNK + tid) * NHEADS + h];
  __syncthreads();
  f32x4 acc[4] = {};
#pragma unroll
  for (int kt = 0; kt < 2; kt++) {
    int ar = w * 16 + (l & 15);
    int kk = kt * 32 + (l >> 4) * 8;
    s16x8 af = *(const s16x8*)&Cl[SWZ(ar, kk)];
#pragma unroll
    for (int nj = 0; nj < 4; nj++) {
      s16x8 bf_ = *(const s16x8*)&Hl[SWZ(nj * 16 + (l & 15), kk)];
      acc[nj] = __builtin_amdgcn_mfma_f32_16x16x32_bf16(af, bf_, acc[nj], 0, 0, 0);
    }
  }
  float Dv = Dsk[h];
  float sq[4] = {0.f, 0.f, 0.f, 0.f};
#pragma unroll
  for (int nj = 0; nj < 4; nj++)
#pragma unroll
    for (int r = 0; r < 4; r++) {
      int t = w * 16 + (l >> 4) * 4 + r;
      int p = nj * 16 + (l & 15);
      size_t gt = c * CHUNK + t;
      size_t gi = gt * D_INNER + h * 64 + p;
      float yv = bf2f(ylg[gi]) + acc[nj][r] * __expf(la_s[t]) +
                 Dv * bf2f(xsb[gt * D_INNER + h * 64 + p]);
      float z = bf2f(zx[gt * D_IN_PROJ + h * 64 + p]);
      short gb = f2bf(yv * silu_f(z));
      ylg[gi] = gb;
      float gf = bf2f(gb);
      sq[r] += gf * gf;  // bf16-rounded g, matching what out_proj will read
    }
  // reduce sq over the 16 lanes sharing (w, l>>4); lane l&15==0 writes partial
#pragma unroll
  for (int r = 0; r < 4; r++) {
    float s = sq[r];
    s += __shfl_xor(s, 1); s += __shfl_xor(s, 2);
    s += __shfl_xor(s, 4); s += __shfl_xor(s, 8);
    if ((l & 15) == 0) {
      int t = w * 16 + (l >> 4) * 4 + r;
      ssqp[(size_t)(c * CHUNK + t) * NHEADS + h] = s;
    }
  }
}

// ----------------------------------------------------------------------------
extern "C" void kernel_launch(void* const* d_in, const int* in_sizes, int n_in,
                              void* d_out, int out_size, void* d_ws, size_t ws_size,
                              hipStream_t stream) {
  const float* x     = (const float*)d_in[0];
  const float* ln1w  = (const float*)d_in[1];
  const float* ln1b  = (const float*)d_in[2];
  const float* ln2w  = (const float*)d_in[3];
  const float* ln2b  = (const float*)d_in[4];
  const float* Win   = (const float*)d_in[5];
  const float* convw = (const float*)d_in[6];
  const float* convb = (const float*)d_in[7];
  const float* dtb   = (const float*)d_in[8];
  const float* Alog  = (const float*)d_in[9];
  const float* Dsk   = (const float*)d_in[10];
  const float* nrmw  = (const float*)d_in[11];
  const float* Wout  = (const float*)d_in[12];
  const float* Wfc1  = (const float*)d_in[13];
  const float* Wfc2  = (const float*)d_in[14];
  float* out = (float*)d_out;

  // ---- workspace layout (~64 MB) ----
  short* zxb   = (short*)d_ws;               // 6,602,752 sh (bf16 zx; reused: gbf)
  short* xsb   = zxb + 6602752;              // 3,145,728 sh
  short* ylg   = xsb + 3145728;              // 3,145,728 sh
  float* Sbf   = (float*)(ylg + 3145728);    // 3,145,728 f region (Sbh; then x1)
  float* dts   = Sbf + 3145728;              // 49,152 f (ssd_a in; then ssqp)
  float* laB   = dts + 49152;                // 49,152 f
  short* hbf   = (short*)(laB + 49152);      // 1,572,864 sh
  short* WA    = hbf + 1572864;              // 2,555,904 sh (Win pad)
  short* WF1   = WA + 2555904;               // 2,359,296 sh (fc1 interleaved)
  short* WB    = WF1 + 2359296;              // 1,179,648 sh (Wout * nw)
  short* WC    = WB + 1179648;               // 1,179,648 sh (Wfc2)
  short* XTall = WC + 1179648;               // 3,145,728 sh (xs^T; then Hsbf)
  short* BTg   = XTall + 3145728;            // 131,072 sh (B^T)
  short* BCbf  = BTg + 131072;               // 262,144 sh

  short* Sbh  = (short*)Sbf;                 // bf16 chunk states (6.3MB of region)
  short* Hsbf = XTall;                       // overlay: XTall dead after ssd_a
  float* x1   = Sbf;                         // overlay: Sbh dead after scan2
  float* ssqp = dts;                         // overlay: dts dead after ssd_a
  short* gbf  = zxb;                         // overlay: zx dead after ssd_b

  // 1) LN1 + all weight casts in one launch (nw folded into Wout)
  cast_ln_kernel<<<SEQ + (T_WINP + T_FC1 + 2 * T_W768 + 255) / 256, 256, 0, stream>>>(
      x, ln1w, ln1b, hbf, Win, Wfc1, Wout, Wfc2, nrmw, WA, WF1, WB, WC);
  // 2) in_proj: zx = h @ Win^T -> bf16 (128x128 tiles, col-chunk swizzle)
  mfma_gemm_bt<4, 4, 0, 1><<<26 * 16, 256, 0, stream>>>(hbf, WA, zxb, nullptr, nullptr,
                                                        26, 16, D_IN_PROJ, D_MODEL);
  // 3) fused conv+silu+pack + dt/la (ct==26)
  conv_pack_kernel<<<dim3(27, 32), 256, 0, stream>>>(zxb, convw, convb, dtb, Alog,
                                                     xsb, XTall, BTg, BCbf, dts, laB);
  // 4) SSD: diag + chunk states, combine, off-diag + gate + ssq partials
  ssd_a_kernel<<<NCHUNK * NHEADS, 256, 0, stream>>>(BCbf, XTall, BTg, laB, dts, ylg, Sbh);
  scan2_kernel<<<(NHEADS * 4096) / 256, 256, 0, stream>>>(Sbh, laB, Hsbf);
  ssd_b_kernel<<<NCHUNK * NHEADS, 256, 0, stream>>>(BCbf, Hsbf, laB, Dsk, xsb, zxb, ylg, ssqp);
  // 5) out_proj with fused RMSNorm + residual: x1 = x + rs*(g @ (Wout.nw)^T)
  mfma_gemm_bt<2, 2, 1, 3><<<12 * 32, 256, 0, stream>>>(ylg, WB, x1, x, ssqp,
                                                        12, 32, D_MODEL, D_INNER);
  // 6) LN2 -> bf16
  ln_kernel<<<SEQ, 256, 0, stream>>>(x1, ln2w, ln2b, hbf);
  // 7) fc1 (interleaved) + fused GLU -> bf16 (col-chunk swizzle)
  mfma_gemm_bt<4, 4, 0, 2><<<24 * 16, 256, 0, stream>>>(hbf, WF1, gbf, nullptr, nullptr,
                                                        24, 16, 2 * HIDDEN, D_MODEL);
  // 8) fc2 + residual: out = x1 + g @ Wfc2^T (row-chunk swizzle)
  mfma_gemm_bt<2, 2, 1, 0><<<12 * 32, 256, 0, stream>>>(gbf, WC, out, x1, nullptr,
                                                        12, 32, D_MODEL, HIDDEN);
}